// Round 1
// baseline (791.005 us; speedup 1.0000x reference)
//
#include <hip/hip_runtime.h>
#include <hip/hip_bf16.h>
#include <cstdint>
#include <cstddef>

#define NN 50000
#define EE 400000

// ---------------- helpers ----------------
static __device__ __forceinline__ float dec_key(unsigned k) {
  return (k & 0x80000000u) ? __uint_as_float(k & 0x7fffffffu) : __uint_as_float(~k);
}
static __device__ __forceinline__ unsigned enc_key(float f) {
  unsigned b = __float_as_uint(f);
  return (f >= 0.f) ? (b | 0x80000000u) : ~b;
}

// ---------------- CSR build ----------------
__global__ void count_kernel(const int* __restrict__ dst, int* __restrict__ cnt, int e) {
  int i = blockIdx.x * blockDim.x + threadIdx.x;
  if (i < e) atomicAdd(&cnt[dst[i]], 1);
}

__global__ void dis_kernel(const int* __restrict__ cnt, float* __restrict__ dis, int n) {
  int i = blockIdx.x * blockDim.x + threadIdx.x;
  if (i < n) dis[i] = rsqrtf((float)cnt[i] + 1.0f);
}

__global__ __launch_bounds__(1024) void scan_kernel(const int* __restrict__ cnt,
                                                    int* __restrict__ rowptr, int n, int total) {
  __shared__ int sm[1024];
  __shared__ int running;
  if (threadIdx.x == 0) running = 0;
  __syncthreads();
  for (int base = 0; base < n; base += 1024) {
    int i = base + threadIdx.x;
    int v = (i < n) ? cnt[i] : 0;
    sm[threadIdx.x] = v;
    __syncthreads();
    for (int off = 1; off < 1024; off <<= 1) {
      int t = (threadIdx.x >= off) ? sm[threadIdx.x - off] : 0;
      __syncthreads();
      sm[threadIdx.x] += t;
      __syncthreads();
    }
    if (i < n) rowptr[i] = running + sm[threadIdx.x] - v;  // exclusive prefix
    __syncthreads();
    if (threadIdx.x == 0) running += sm[1023];
    __syncthreads();
  }
  if (threadIdx.x == 0) rowptr[n] = total;
}

__global__ void fill_kernel(const int* __restrict__ src, const int* __restrict__ dst,
                            const int* __restrict__ rowptr, int* __restrict__ cursor,
                            int* __restrict__ col, int e) {
  int i = blockIdx.x * blockDim.x + threadIdx.x;
  if (i < e) {
    int d = dst[i];
    int p = atomicAdd(&cursor[d], 1);
    col[rowptr[d] + p] = src[i];
  }
}

// ---------------- GEMM: C[M,Nout] = A[M,K] @ W[K,Nout] (+crow) (+C if accumulate) ----------------
#define BM 64
#define BN 64
#define BK 16

__global__ __launch_bounds__(256) void gemm_f32(
    const float* __restrict__ A, const float* __restrict__ W, float* __restrict__ C,
    int M, int K, int Nout, const float* __restrict__ crow, int accumulate) {
  __shared__ float As[BK][BM + 4];  // transposed A tile, padded to keep 16B align + spread banks
  __shared__ float Ws[BK][BN];
  int tid = threadIdx.x;
  int row0 = blockIdx.x * BM;
  int col0 = blockIdx.y * BN;
  int tx = tid & 15;
  int ty = tid >> 4;
  float acc[4][4] = {};
  for (int k0 = 0; k0 < K; k0 += BK) {
#pragma unroll
    for (int i = 0; i < 4; ++i) {
      int idx = tid + i * 256;
      int r = idx >> 4, c = idx & 15;
      int gr = row0 + r;
      float v = (gr < M) ? A[(size_t)gr * K + k0 + c] : 0.f;
      As[c][r] = v;
    }
#pragma unroll
    for (int i = 0; i < 4; ++i) {
      int idx = tid + i * 256;
      int r = idx >> 6, c = idx & 63;
      Ws[r][c] = W[(size_t)(k0 + r) * Nout + col0 + c];
    }
    __syncthreads();
#pragma unroll
    for (int kk = 0; kk < BK; ++kk) {
      float4 av = *(const float4*)&As[kk][ty * 4];
      float4 wv = *(const float4*)&Ws[kk][tx * 4];
      float a[4] = {av.x, av.y, av.z, av.w};
      float w[4] = {wv.x, wv.y, wv.z, wv.w};
#pragma unroll
      for (int i = 0; i < 4; ++i)
#pragma unroll
        for (int j = 0; j < 4; ++j) acc[i][j] = fmaf(a[i], w[j], acc[i][j]);
    }
    __syncthreads();
  }
#pragma unroll
  for (int i = 0; i < 4; ++i) {
    int gr = row0 + ty * 4 + i;
    if (gr >= M) continue;
#pragma unroll
    for (int j = 0; j < 4; ++j) {
      int gc = col0 + tx * 4 + j;
      float base = 0.f;
      if (crow) base = crow[gc];
      if (accumulate) base += C[(size_t)gr * Nout + gc];
      C[(size_t)gr * Nout + gc] = acc[i][j] + base;
    }
  }
}

// ---------------- aggregation: out[d] = tanh( sum_{s in N(d)} H[s]*dis[s]*dis[d] + H[d]*dis[d]^2 + b ) ----------------
template <int F>
__global__ __launch_bounds__(256) void agg_kernel(
    const float* __restrict__ H, const int* __restrict__ rowptr, const int* __restrict__ col,
    const float* __restrict__ dis, const float* __restrict__ bias, float* __restrict__ out, int n) {
  constexpr int VEC = F / 64;
  int wid = (int)((blockIdx.x * blockDim.x + threadIdx.x) >> 6);
  int lane = threadIdx.x & 63;
  if (wid >= n) return;
  int node = __builtin_amdgcn_readfirstlane(wid);
  float dd = dis[node];
  float acc[VEC];
  {
    const float* hs = H + (size_t)node * F + lane * VEC;
    if constexpr (VEC == 4) {
      float4 h = *(const float4*)hs;
      acc[0] = h.x * dd * dd; acc[1] = h.y * dd * dd; acc[2] = h.z * dd * dd; acc[3] = h.w * dd * dd;
    } else {
      float2 h = *(const float2*)hs;
      acc[0] = h.x * dd * dd; acc[1] = h.y * dd * dd;
    }
  }
  int beg = rowptr[node], end = rowptr[node + 1];
  for (int e = beg; e < end; ++e) {
    int s = col[e];
    float w = dis[s] * dd;
    const float* hs = H + (size_t)s * F + lane * VEC;
    if constexpr (VEC == 4) {
      float4 h = *(const float4*)hs;
      acc[0] = fmaf(h.x, w, acc[0]); acc[1] = fmaf(h.y, w, acc[1]);
      acc[2] = fmaf(h.z, w, acc[2]); acc[3] = fmaf(h.w, w, acc[3]);
    } else {
      float2 h = *(const float2*)hs;
      acc[0] = fmaf(h.x, w, acc[0]); acc[1] = fmaf(h.y, w, acc[1]);
    }
  }
  float* o = out + (size_t)node * F + lane * VEC;
#pragma unroll
  for (int i = 0; i < VEC; ++i) o[i] = tanhf(acc[i] + bias[lane * VEC + i]);
}

// ---------------- per-feature global max (encoded atomicMax) ----------------
__global__ __launch_bounds__(256) void colmax_kernel(const float* __restrict__ T,
                                                     unsigned* __restrict__ maxkey, int n) {
  int f = threadIdx.x;  // F = 256
  float m = -2.0f;      // tanh outputs are in (-1,1)
  for (int r = blockIdx.x; r < n; r += gridDim.x) m = fmaxf(m, T[(size_t)r * 256 + f]);
  atomicMax(&maxkey[f], enc_key(m));
}

// const row = i1vec @ W7[0:256,:]
__global__ __launch_bounds__(128) void crow_kernel(const unsigned* __restrict__ maxkey,
                                                   const float* __restrict__ W7top,
                                                   float* __restrict__ crow) {
  int j = threadIdx.x;  // 128
  float s = 0.f;
  for (int f = 0; f < 256; ++f) s = fmaf(dec_key(maxkey[f]), W7top[f * 128 + j], s);
  crow[j] = s;
}

// ---------------- launch ----------------
extern "C" void kernel_launch(void* const* d_in, const int* in_sizes, int n_in,
                              void* d_out, int out_size, void* d_ws, size_t ws_size,
                              hipStream_t stream) {
  const float* x  = (const float*)d_in[0];
  const int* ei   = (const int*)d_in[1];
  const int* srcp = ei;
  const int* dstp = ei + EE;
  const float* W1 = (const float*)d_in[3];
  const float* b1 = (const float*)d_in[4];
  const float* W2 = (const float*)d_in[5];
  const float* b2 = (const float*)d_in[6];
  const float* W3 = (const float*)d_in[7];
  const float* b3 = (const float*)d_in[8];
  const float* W4 = (const float*)d_in[9];
  const float* b4 = (const float*)d_in[10];
  const float* W7 = (const float*)d_in[11];
  const float* b7 = (const float*)d_in[12];
  float* out = (float*)d_out;

  char* p = (char*)d_ws;
  auto alloc = [&](size_t bytes) -> void* {
    void* r = (void*)p;
    p += (bytes + 255) & ~(size_t)255;
    return r;
  };
  float* H = (float*)alloc((size_t)NN * 256 * 4);
  float* A = (float*)alloc((size_t)NN * 256 * 4);
  float* B = (float*)alloc((size_t)NN * 256 * 4);
  float* dis = (float*)alloc((size_t)NN * 4);
  int* cnt = (int*)alloc((size_t)NN * 4);
  int* cursor = (int*)alloc((size_t)NN * 4);
  int* rowptr = (int*)alloc((size_t)(NN + 1) * 4);
  int* col = (int*)alloc((size_t)EE * 4);
  unsigned* maxkey = (unsigned*)alloc(256 * 4);
  float* crow = (float*)alloc(128 * 4);

  hipMemsetAsync(cnt, 0, (size_t)NN * 4, stream);
  hipMemsetAsync(cursor, 0, (size_t)NN * 4, stream);
  hipMemsetAsync(maxkey, 0, 256 * 4, stream);

  int eb = (EE + 255) / 256;
  int nb = (NN + 255) / 256;
  count_kernel<<<eb, 256, 0, stream>>>(dstp, cnt, EE);
  dis_kernel<<<nb, 256, 0, stream>>>(cnt, dis, NN);
  scan_kernel<<<1, 1024, 0, stream>>>(cnt, rowptr, NN, EE);
  fill_kernel<<<eb, 256, 0, stream>>>(srcp, dstp, rowptr, cursor, col, EE);

  dim3 gB(256);
  int mrows = (NN + BM - 1) / BM;  // 782
  int aggB = (NN + 3) / 4;         // 12500 blocks, 1 wave/node

  // stage 1: t1 = tanh(agg(x@W1)+b1) -> A  [N,128]
  gemm_f32<<<dim3(mrows, 2), gB, 0, stream>>>(x, W1, H, NN, 64, 128, nullptr, 0);
  agg_kernel<128><<<aggB, gB, 0, stream>>>(H, rowptr, col, dis, b1, A, NN);
  // stage 2: t2 = tanh(agg(t1@W2)+b2) -> A (t1 dead after gemm)  [N,256]
  gemm_f32<<<dim3(mrows, 4), gB, 0, stream>>>(A, W2, H, NN, 128, 256, nullptr, 0);
  agg_kernel<256><<<aggB, gB, 0, stream>>>(H, rowptr, col, dis, b2, A, NN);
  colmax_kernel<<<256, gB, 0, stream>>>(A, maxkey, NN);
  // stage 3: t3 = tanh(agg(x@W3)+b3) -> B  [N,128]
  gemm_f32<<<dim3(mrows, 2), gB, 0, stream>>>(x, W3, H, NN, 64, 128, nullptr, 0);
  agg_kernel<128><<<aggB, gB, 0, stream>>>(H, rowptr, col, dis, b3, B, NN);
  // stage 4: i2 = tanh(agg(t3@W4)+b4) -> A  [N,256]
  gemm_f32<<<dim3(mrows, 4), gB, 0, stream>>>(B, W4, H, NN, 128, 256, nullptr, 0);
  agg_kernel<256><<<aggB, gB, 0, stream>>>(H, rowptr, col, dis, b4, A, NN);
  // stage 5: out = tanh(agg(i1vec@W7a + i2@W7b + x@W7c) + b7)
  crow_kernel<<<1, 128, 0, stream>>>(maxkey, W7, crow);
  gemm_f32<<<dim3(mrows, 2), gB, 0, stream>>>(A, W7 + 256 * 128, H, NN, 256, 128, crow, 0);
  gemm_f32<<<dim3(mrows, 2), gB, 0, stream>>>(x, W7 + 512 * 128, H, NN, 64, 128, nullptr, 1);
  agg_kernel<128><<<aggB, gB, 0, stream>>>(H, rowptr, col, dis, b7, out, NN);
}

// Round 3
// 710.368 us; speedup vs baseline: 1.1135x; 1.1135x over previous
//
#include <hip/hip_runtime.h>
#include <hip/hip_bf16.h>
#include <cstdint>
#include <cstddef>

#define NN 50000
#define EE 400000

// ---------------- helpers ----------------
static __device__ __forceinline__ float dec_key(unsigned k) {
  return (k & 0x80000000u) ? __uint_as_float(k & 0x7fffffffu) : __uint_as_float(~k);
}
static __device__ __forceinline__ unsigned enc_key(float f) {
  unsigned b = __float_as_uint(f);
  return (f >= 0.f) ? (b | 0x80000000u) : ~b;
}

// ---------------- CSR build ----------------
__global__ void count_kernel(const int* __restrict__ dst, int* __restrict__ cnt, int e) {
  int i = blockIdx.x * blockDim.x + threadIdx.x;
  if (i < e) atomicAdd(&cnt[dst[i]], 1);
}

__global__ void dis_kernel(const int* __restrict__ cnt, float* __restrict__ dis, int n) {
  int i = blockIdx.x * blockDim.x + threadIdx.x;
  if (i < n) dis[i] = rsqrtf((float)cnt[i] + 1.0f);
}

// hierarchical scan: 1024 elems per block (4/thread), shuffle wave-scan
#define SCAN_CHUNK 1024
__global__ __launch_bounds__(256) void scan1_kernel(const int* __restrict__ cnt,
                                                    int* __restrict__ rowptr,
                                                    int* __restrict__ bsum, int n) {
  int b = blockIdx.x;
  int base = b * SCAN_CHUNK;
  int t = threadIdx.x;
  int v[4];
  int s = 0;
#pragma unroll
  for (int i = 0; i < 4; ++i) {
    int idx = base + t * 4 + i;
    v[i] = (idx < n) ? cnt[idx] : 0;
    s += v[i];
  }
  int lane = t & 63, w = t >> 6;
  int inc = s;
#pragma unroll
  for (int off = 1; off < 64; off <<= 1) {
    int o = __shfl_up(inc, off, 64);
    if (lane >= off) inc += o;
  }
  __shared__ int wsum[4];
  if (lane == 63) wsum[w] = inc;
  __syncthreads();
  int woff = 0;
  for (int i = 0; i < w; ++i) woff += wsum[i];
  int run = woff + inc - s;  // exclusive prefix of this thread's 4-group
#pragma unroll
  for (int i = 0; i < 4; ++i) {
    int idx = base + t * 4 + i;
    if (idx < n) rowptr[idx] = run;
    run += v[i];
  }
  if (t == 255) bsum[b] = woff + inc;  // block total
}

__global__ void scan2_kernel(int* __restrict__ bsum, int nb) {
  int t = threadIdx.x;  // single wave of 64, nb <= 64
  int v = (t < nb) ? bsum[t] : 0;
  int s = v;
#pragma unroll
  for (int off = 1; off < 64; off <<= 1) {
    int o = __shfl_up(s, off, 64);
    if (t >= off) s += o;
  }
  if (t < nb) bsum[t] = s - v;  // exclusive
}

__global__ __launch_bounds__(256) void scan3_kernel(int* __restrict__ rowptr,
                                                    const int* __restrict__ bsum, int n, int total) {
  int i = blockIdx.x * blockDim.x + threadIdx.x;
  if (i < n) rowptr[i] += bsum[i >> 10];
  if (i == 0) rowptr[n] = total;
}

__global__ void fill_kernel(const int* __restrict__ src, const int* __restrict__ dst,
                            const int* __restrict__ rowptr, int* __restrict__ cursor,
                            int* __restrict__ col, int e) {
  int i = blockIdx.x * blockDim.x + threadIdx.x;
  if (i < e) {
    int d = dst[i];
    int p = atomicAdd(&cursor[d], 1);
    col[rowptr[d] + p] = src[i];
  }
}

// ---------------- GEMM: C[M,Nout] = A[M,K] @ W[K,Nout] (+crow) (+C if accumulate) ----------------
#define BM 64
#define BN 64
#define BK 16

__global__ __launch_bounds__(256) void gemm_f32(
    const float* __restrict__ A, const float* __restrict__ W, float* __restrict__ C,
    int M, int K, int Nout, const float* __restrict__ crow, int accumulate) {
  __shared__ float As[BK][BM + 4];
  __shared__ float Ws[BK][BN];
  int tid = threadIdx.x;
  int row0 = blockIdx.x * BM;
  int col0 = blockIdx.y * BN;
  int tx = tid & 15;
  int ty = tid >> 4;
  float acc[4][4] = {};
  for (int k0 = 0; k0 < K; k0 += BK) {
#pragma unroll
    for (int i = 0; i < 4; ++i) {
      int idx = tid + i * 256;
      int r = idx >> 4, c = idx & 15;
      int gr = row0 + r;
      float v = (gr < M) ? A[(size_t)gr * K + k0 + c] : 0.f;
      As[c][r] = v;
    }
#pragma unroll
    for (int i = 0; i < 4; ++i) {
      int idx = tid + i * 256;
      int r = idx >> 6, c = idx & 63;
      Ws[r][c] = W[(size_t)(k0 + r) * Nout + col0 + c];
    }
    __syncthreads();
#pragma unroll
    for (int kk = 0; kk < BK; ++kk) {
      float4 av = *(const float4*)&As[kk][ty * 4];
      float4 wv = *(const float4*)&Ws[kk][tx * 4];
      float a[4] = {av.x, av.y, av.z, av.w};
      float w[4] = {wv.x, wv.y, wv.z, wv.w};
#pragma unroll
      for (int i = 0; i < 4; ++i)
#pragma unroll
        for (int j = 0; j < 4; ++j) acc[i][j] = fmaf(a[i], w[j], acc[i][j]);
    }
    __syncthreads();
  }
#pragma unroll
  for (int i = 0; i < 4; ++i) {
    int gr = row0 + ty * 4 + i;
    if (gr >= M) continue;
#pragma unroll
    for (int j = 0; j < 4; ++j) {
      int gc = col0 + tx * 4 + j;
      float base = 0.f;
      if (crow) base = crow[gc];
      if (accumulate) base += C[(size_t)gr * Nout + gc];
      C[(size_t)gr * Nout + gc] = acc[i][j] + base;
    }
  }
}

// ---------------- aggregation ----------------
template <int F>
__global__ __launch_bounds__(256) void agg_kernel(
    const float* __restrict__ H, const int* __restrict__ rowptr, const int* __restrict__ col,
    const float* __restrict__ dis, const float* __restrict__ bias, float* __restrict__ out, int n) {
  constexpr int VEC = F / 64;
  int wid = (int)((blockIdx.x * blockDim.x + threadIdx.x) >> 6);
  int lane = threadIdx.x & 63;
  if (wid >= n) return;
  int node = __builtin_amdgcn_readfirstlane(wid);
  float dd = dis[node];
  float acc[VEC];
  {
    const float* hs = H + (size_t)node * F + lane * VEC;
    if constexpr (VEC == 4) {
      float4 h = *(const float4*)hs;
      acc[0] = h.x * dd * dd; acc[1] = h.y * dd * dd; acc[2] = h.z * dd * dd; acc[3] = h.w * dd * dd;
    } else {
      float2 h = *(const float2*)hs;
      acc[0] = h.x * dd * dd; acc[1] = h.y * dd * dd;
    }
  }
  int beg = rowptr[node], end = rowptr[node + 1];
  for (int e = beg; e < end; ++e) {
    int s = col[e];
    float w = dis[s] * dd;
    const float* hs = H + (size_t)s * F + lane * VEC;
    if constexpr (VEC == 4) {
      float4 h = *(const float4*)hs;
      acc[0] = fmaf(h.x, w, acc[0]); acc[1] = fmaf(h.y, w, acc[1]);
      acc[2] = fmaf(h.z, w, acc[2]); acc[3] = fmaf(h.w, w, acc[3]);
    } else {
      float2 h = *(const float2*)hs;
      acc[0] = fmaf(h.x, w, acc[0]); acc[1] = fmaf(h.y, w, acc[1]);
    }
  }
  float* o = out + (size_t)node * F + lane * VEC;
#pragma unroll
  for (int i = 0; i < VEC; ++i) o[i] = tanhf(acc[i] + bias[lane * VEC + i]);
}

// ---------------- per-feature global max ----------------
__global__ __launch_bounds__(256) void colmax_kernel(const float* __restrict__ T,
                                                     unsigned* __restrict__ maxkey, int n) {
  int f = threadIdx.x;  // F = 256
  float m = -2.0f;
  for (int r = blockIdx.x; r < n; r += gridDim.x) m = fmaxf(m, T[(size_t)r * 256 + f]);
  atomicMax(&maxkey[f], enc_key(m));
}

__global__ __launch_bounds__(128) void crow_kernel(const unsigned* __restrict__ maxkey,
                                                   const float* __restrict__ W7top,
                                                   float* __restrict__ crow) {
  int j = threadIdx.x;  // 128
  float s = 0.f;
  for (int f = 0; f < 256; ++f) s = fmaf(dec_key(maxkey[f]), W7top[f * 128 + j], s);
  crow[j] = s;
}

// ---------------- launch ----------------
extern "C" void kernel_launch(void* const* d_in, const int* in_sizes, int n_in,
                              void* d_out, int out_size, void* d_ws, size_t ws_size,
                              hipStream_t stream) {
  const float* x  = (const float*)d_in[0];
  const int* ei   = (const int*)d_in[1];
  const int* srcp = ei;
  const int* dstp = ei + EE;
  const float* W1 = (const float*)d_in[3];
  const float* b1 = (const float*)d_in[4];
  const float* W2 = (const float*)d_in[5];
  const float* b2 = (const float*)d_in[6];
  const float* W3 = (const float*)d_in[7];
  const float* b3 = (const float*)d_in[8];
  const float* W4 = (const float*)d_in[9];
  const float* b4 = (const float*)d_in[10];
  const float* W7 = (const float*)d_in[11];
  const float* b7 = (const float*)d_in[12];
  float* out = (float*)d_out;

  char* p = (char*)d_ws;
  auto alloc = [&](size_t bytes) -> void* {
    void* r = (void*)p;
    p += (bytes + 255) & ~(size_t)255;
    return r;
  };
  float* H = (float*)alloc((size_t)NN * 256 * 4);
  float* A = (float*)alloc((size_t)NN * 256 * 4);
  float* B = (float*)alloc((size_t)NN * 256 * 4);
  float* dis = (float*)alloc((size_t)NN * 4);
  int* cnt = (int*)alloc((size_t)NN * 4);
  int* cursor = (int*)alloc((size_t)NN * 4);
  int* rowptr = (int*)alloc((size_t)(NN + 1) * 4);
  int* col = (int*)alloc((size_t)EE * 4);
  int* bsum = (int*)alloc(64 * 4);
  unsigned* maxkey = (unsigned*)alloc(256 * 4);
  float* crow = (float*)alloc(128 * 4);

  hipMemsetAsync(cnt, 0, (size_t)NN * 4, stream);
  hipMemsetAsync(cursor, 0, (size_t)NN * 4, stream);
  hipMemsetAsync(maxkey, 0, 256 * 4, stream);

  int eb = (EE + 255) / 256;
  int nb = (NN + 255) / 256;
  int nchunks = (NN + SCAN_CHUNK - 1) / SCAN_CHUNK;  // 49
  count_kernel<<<eb, 256, 0, stream>>>(dstp, cnt, EE);
  dis_kernel<<<nb, 256, 0, stream>>>(cnt, dis, NN);
  scan1_kernel<<<nchunks, 256, 0, stream>>>(cnt, rowptr, bsum, NN);
  scan2_kernel<<<1, 64, 0, stream>>>(bsum, nchunks);
  scan3_kernel<<<nb, 256, 0, stream>>>(rowptr, bsum, NN, EE);
  fill_kernel<<<eb, 256, 0, stream>>>(srcp, dstp, rowptr, cursor, col, EE);

  dim3 gB(256);
  int mrows = (NN + BM - 1) / BM;  // 782
  int aggB = (NN + 3) / 4;         // 12500 blocks, 1 wave/node

  // stage 1: t1 = tanh(agg(x@W1)+b1) -> A  [N,128]
  gemm_f32<<<dim3(mrows, 2), gB, 0, stream>>>(x, W1, H, NN, 64, 128, nullptr, 0);
  agg_kernel<128><<<aggB, gB, 0, stream>>>(H, rowptr, col, dis, b1, A, NN);
  // stage 2: t2 = tanh(agg(t1@W2)+b2) -> A  [N,256]
  gemm_f32<<<dim3(mrows, 4), gB, 0, stream>>>(A, W2, H, NN, 128, 256, nullptr, 0);
  agg_kernel<256><<<aggB, gB, 0, stream>>>(H, rowptr, col, dis, b2, A, NN);
  colmax_kernel<<<256, gB, 0, stream>>>(A, maxkey, NN);
  // stage 3: t3 = tanh(agg(x@W3)+b3) -> B  [N,128]
  gemm_f32<<<dim3(mrows, 2), gB, 0, stream>>>(x, W3, H, NN, 64, 128, nullptr, 0);
  agg_kernel<128><<<aggB, gB, 0, stream>>>(H, rowptr, col, dis, b3, B, NN);
  // stage 4: i2 = tanh(agg(t3@W4)+b4) -> A  [N,256]
  gemm_f32<<<dim3(mrows, 4), gB, 0, stream>>>(B, W4, H, NN, 128, 256, nullptr, 0);
  agg_kernel<256><<<aggB, gB, 0, stream>>>(H, rowptr, col, dis, b4, A, NN);
  // stage 5: out = tanh(agg(i1vec@W7a + i2@W7b + x@W7c) + b7)
  crow_kernel<<<1, 128, 0, stream>>>(maxkey, W7, crow);
  gemm_f32<<<dim3(mrows, 2), gB, 0, stream>>>(A, W7 + 256 * 128, H, NN, 256, 128, crow, 0);
  gemm_f32<<<dim3(mrows, 2), gB, 0, stream>>>(x, W7 + 512 * 128, H, NN, 64, 128, nullptr, 1);
  agg_kernel<128><<<aggB, gB, 0, stream>>>(H, rowptr, col, dis, b7, out, NN);
}

// Round 6
// 616.604 us; speedup vs baseline: 1.2828x; 1.1521x over previous
//
#include <hip/hip_runtime.h>
#include <hip/hip_bf16.h>
#include <cstdint>
#include <cstddef>

#define NN 50000
#define EE 400000

// ---------------- helpers ----------------
static __device__ __forceinline__ float dec_key(unsigned k) {
  return (k & 0x80000000u) ? __uint_as_float(k & 0x7fffffffu) : __uint_as_float(~k);
}
static __device__ __forceinline__ unsigned enc_key(float f) {
  unsigned b = __float_as_uint(f);
  return (f >= 0.f) ? (b | 0x80000000u) : ~b;
}

// ---------------- CSR build ----------------
__global__ void count_kernel(const int* __restrict__ dst, int* __restrict__ cnt, int e) {
  int i = blockIdx.x * blockDim.x + threadIdx.x;
  if (i < e) atomicAdd(&cnt[dst[i]], 1);
}

__global__ void dis_kernel(const int* __restrict__ cnt, float* __restrict__ dis, int n) {
  int i = blockIdx.x * blockDim.x + threadIdx.x;
  if (i < n) dis[i] = rsqrtf((float)cnt[i] + 1.0f);
}

// hierarchical scan: 1024 elems per block (4/thread), shuffle wave-scan
#define SCAN_CHUNK 1024
__global__ __launch_bounds__(256) void scan1_kernel(const int* __restrict__ cnt,
                                                    int* __restrict__ rowptr,
                                                    int* __restrict__ bsum, int n) {
  int b = blockIdx.x;
  int base = b * SCAN_CHUNK;
  int t = threadIdx.x;
  int v[4];
  int s = 0;
#pragma unroll
  for (int i = 0; i < 4; ++i) {
    int idx = base + t * 4 + i;
    v[i] = (idx < n) ? cnt[idx] : 0;
    s += v[i];
  }
  int lane = t & 63, w = t >> 6;
  int inc = s;
#pragma unroll
  for (int off = 1; off < 64; off <<= 1) {
    int o = __shfl_up(inc, off, 64);
    if (lane >= off) inc += o;
  }
  __shared__ int wsum[4];
  if (lane == 63) wsum[w] = inc;
  __syncthreads();
  int woff = 0;
  for (int i = 0; i < w; ++i) woff += wsum[i];
  int run = woff + inc - s;
#pragma unroll
  for (int i = 0; i < 4; ++i) {
    int idx = base + t * 4 + i;
    if (idx < n) rowptr[idx] = run;
    run += v[i];
  }
  if (t == 255) bsum[b] = woff + inc;
}

__global__ void scan2_kernel(int* __restrict__ bsum, int nb) {
  int t = threadIdx.x;
  int v = (t < nb) ? bsum[t] : 0;
  int s = v;
#pragma unroll
  for (int off = 1; off < 64; off <<= 1) {
    int o = __shfl_up(s, off, 64);
    if (t >= off) s += o;
  }
  if (t < nb) bsum[t] = s - v;
}

__global__ __launch_bounds__(256) void scan3_kernel(int* __restrict__ rowptr,
                                                    const int* __restrict__ bsum, int n, int total) {
  int i = blockIdx.x * blockDim.x + threadIdx.x;
  if (i < n) rowptr[i] += bsum[i >> 10];
  if (i == 0) rowptr[n] = total;
}

__global__ void fill_kernel(const int* __restrict__ src, const int* __restrict__ dst,
                            const int* __restrict__ rowptr, int* __restrict__ cursor,
                            int* __restrict__ col, int e) {
  int i = blockIdx.x * blockDim.x + threadIdx.x;
  if (i < e) {
    int d = dst[i];
    int p = atomicAdd(&cursor[d], 1);
    col[rowptr[d] + p] = src[i];
  }
}

// ---------------- GEMM: C[M,Nout] = A[M,K] @ W[K,Nout], fused epilogue ----------------
#define BM 64
#define BN 64
#define BK 16

__global__ __launch_bounds__(256) void gemm_f32(
    const float* __restrict__ A, const float* __restrict__ W, float* __restrict__ C,
    int M, int K, int Nout, const float* __restrict__ colAdd, int accumulate, int doTanh) {
  __shared__ float As[BK][BM + 4];
  __shared__ float Ws[BK][BN];
  int tid = threadIdx.x;
  int row0 = blockIdx.x * BM;
  int col0 = blockIdx.y * BN;
  int tx = tid & 15;
  int ty = tid >> 4;
  float acc[4][4] = {};
  for (int k0 = 0; k0 < K; k0 += BK) {
#pragma unroll
    for (int i = 0; i < 4; ++i) {
      int idx = tid + i * 256;
      int r = idx >> 4, c = idx & 15;
      int gr = row0 + r;
      float v = (gr < M) ? A[(size_t)gr * K + k0 + c] : 0.f;
      As[c][r] = v;
    }
#pragma unroll
    for (int i = 0; i < 4; ++i) {
      int idx = tid + i * 256;
      int r = idx >> 6, c = idx & 63;
      Ws[r][c] = W[(size_t)(k0 + r) * Nout + col0 + c];
    }
    __syncthreads();
#pragma unroll
    for (int kk = 0; kk < BK; ++kk) {
      float4 av = *(const float4*)&As[kk][ty * 4];
      float4 wv = *(const float4*)&Ws[kk][tx * 4];
      float a[4] = {av.x, av.y, av.z, av.w};
      float w[4] = {wv.x, wv.y, wv.z, wv.w};
#pragma unroll
      for (int i = 0; i < 4; ++i)
#pragma unroll
        for (int j = 0; j < 4; ++j) acc[i][j] = fmaf(a[i], w[j], acc[i][j]);
    }
    __syncthreads();
  }
#pragma unroll
  for (int i = 0; i < 4; ++i) {
    int gr = row0 + ty * 4 + i;
    if (gr >= M) continue;
#pragma unroll
    for (int j = 0; j < 4; ++j) {
      int gc = col0 + tx * 4 + j;
      size_t idx = (size_t)gr * Nout + gc;
      float v = acc[i][j];
      if (colAdd) v += colAdd[gc];
      if (accumulate) v += C[idx];
      if (doTanh) v = tanhf(v);
      C[idx] = v;
    }
  }
}

// ---------------- aggregation: out[d] = sum_{s in N(d)} H[s]*dis[s]*dis[d] + H[d]*dis[d]^2 ----------------
// EPI: add bias + tanh in epilogue (only used for final stage)
template <int F, bool EPI>
__global__ __launch_bounds__(256) void agg_kernel(
    const float* __restrict__ H, const int* __restrict__ rowptr, const int* __restrict__ col,
    const float* __restrict__ dis, const float* __restrict__ bias, float* __restrict__ out, int n) {
  constexpr int VEC = F / 64;
  int wid = (int)((blockIdx.x * blockDim.x + threadIdx.x) >> 6);
  int lane = threadIdx.x & 63;
  if (wid >= n) return;
  int node = __builtin_amdgcn_readfirstlane(wid);
  float dd = dis[node];
  float acc[VEC];
  {
    const float* hs = H + (size_t)node * F + lane * VEC;
    if constexpr (VEC == 4) {
      float4 h = *(const float4*)hs;
      acc[0] = h.x * dd * dd; acc[1] = h.y * dd * dd; acc[2] = h.z * dd * dd; acc[3] = h.w * dd * dd;
    } else if constexpr (VEC == 2) {
      float2 h = *(const float2*)hs;
      acc[0] = h.x * dd * dd; acc[1] = h.y * dd * dd;
    } else {
      acc[0] = hs[0] * dd * dd;
    }
  }
  int beg = rowptr[node], end = rowptr[node + 1];
  for (int e = beg; e < end; ++e) {
    int s = col[e];
    float w = dis[s] * dd;
    const float* hs = H + (size_t)s * F + lane * VEC;
    if constexpr (VEC == 4) {
      float4 h = *(const float4*)hs;
      acc[0] = fmaf(h.x, w, acc[0]); acc[1] = fmaf(h.y, w, acc[1]);
      acc[2] = fmaf(h.z, w, acc[2]); acc[3] = fmaf(h.w, w, acc[3]);
    } else if constexpr (VEC == 2) {
      float2 h = *(const float2*)hs;
      acc[0] = fmaf(h.x, w, acc[0]); acc[1] = fmaf(h.y, w, acc[1]);
    } else {
      acc[0] = fmaf(hs[0], w, acc[0]);
    }
  }
  float* o = out + (size_t)node * F + lane * VEC;
#pragma unroll
  for (int i = 0; i < VEC; ++i) {
    float v = acc[i];
    if constexpr (EPI) v = tanhf(v + bias[lane * VEC + i]);
    o[i] = v;
  }
}

// ---------------- per-feature global max ----------------
__global__ __launch_bounds__(256) void colmax_kernel(const float* __restrict__ T,
                                                     unsigned* __restrict__ maxkey, int n) {
  int f = threadIdx.x;  // F = 256
  float m = -2.0f;
  for (int r = blockIdx.x; r < n; r += gridDim.x) m = fmaxf(m, T[(size_t)r * 256 + f]);
  atomicMax(&maxkey[f], enc_key(m));
}

__global__ __launch_bounds__(128) void crow_kernel(const unsigned* __restrict__ maxkey,
                                                   const float* __restrict__ W7top,
                                                   float* __restrict__ crow) {
  int j = threadIdx.x;  // 128
  float s = 0.f;
  for (int f = 0; f < 256; ++f) s = fmaf(dec_key(maxkey[f]), W7top[f * 128 + j], s);
  crow[j] = s;
}

// ---------------- launch ----------------
extern "C" void kernel_launch(void* const* d_in, const int* in_sizes, int n_in,
                              void* d_out, int out_size, void* d_ws, size_t ws_size,
                              hipStream_t stream) {
  const float* x  = (const float*)d_in[0];
  const int* ei   = (const int*)d_in[1];
  const int* srcp = ei;
  const int* dstp = ei + EE;
  const float* W1 = (const float*)d_in[3];
  const float* b1 = (const float*)d_in[4];
  const float* W2 = (const float*)d_in[5];
  const float* b2 = (const float*)d_in[6];
  const float* W3 = (const float*)d_in[7];
  const float* b3 = (const float*)d_in[8];
  const float* W4 = (const float*)d_in[9];
  const float* b4 = (const float*)d_in[10];
  const float* W7 = (const float*)d_in[11];
  const float* b7 = (const float*)d_in[12];
  float* out = (float*)d_out;

  char* p = (char*)d_ws;
  auto alloc = [&](size_t bytes) -> void* {
    void* r = (void*)p;
    p += (bytes + 255) & ~(size_t)255;
    return r;
  };
  float* H  = (float*)alloc((size_t)NN * 256 * 4);  // aggregate / G buffer
  float* A  = (float*)alloc((size_t)NN * 128 * 4);  // t1 / t3
  float* B  = (float*)alloc((size_t)NN * 256 * 4);  // t2 / i2
  float* AX = (float*)alloc((size_t)NN * 64 * 4);   // agg(x), reused 2x
  float* dis = (float*)alloc((size_t)NN * 4);
  int* cnt = (int*)alloc((size_t)NN * 4);
  int* cursor = (int*)alloc((size_t)NN * 4);
  int* rowptr = (int*)alloc((size_t)(NN + 1) * 4);
  int* col = (int*)alloc((size_t)EE * 4);
  int* bsum = (int*)alloc(64 * 4);
  unsigned* maxkey = (unsigned*)alloc(256 * 4);
  float* crow = (float*)alloc(128 * 4);

  hipMemsetAsync(cnt, 0, (size_t)NN * 4, stream);
  hipMemsetAsync(cursor, 0, (size_t)NN * 4, stream);
  hipMemsetAsync(maxkey, 0, 256 * 4, stream);

  int eb = (EE + 255) / 256;
  int nb = (NN + 255) / 256;
  int nchunks = (NN + SCAN_CHUNK - 1) / SCAN_CHUNK;
  count_kernel<<<eb, 256, 0, stream>>>(dstp, cnt, EE);
  dis_kernel<<<nb, 256, 0, stream>>>(cnt, dis, NN);
  scan1_kernel<<<nchunks, 256, 0, stream>>>(cnt, rowptr, bsum, NN);
  scan2_kernel<<<1, 64, 0, stream>>>(bsum, nchunks);
  scan3_kernel<<<nb, 256, 0, stream>>>(rowptr, bsum, NN, EE);
  fill_kernel<<<eb, 256, 0, stream>>>(srcp, dstp, rowptr, cursor, col, EE);

  dim3 gB(256);
  int mrows = (NN + BM - 1) / BM;  // 782
  int aggB = (NN + 3) / 4;         // 1 wave/node

  // AX = agg(x)  [N,64] — shared by stages 1, 3
  agg_kernel<64, false><<<aggB, gB, 0, stream>>>(x, rowptr, col, dis, nullptr, AX, NN);
  // stage 1: t1 = tanh(AX@W1 + b1) -> A  [N,128]
  gemm_f32<<<dim3(mrows, 2), gB, 0, stream>>>(AX, W1, A, NN, 64, 128, b1, 0, 1);
  // stage 2: A1 = agg(t1); t2 = tanh(A1@W2 + b2) -> B  [N,256]
  agg_kernel<128, false><<<aggB, gB, 0, stream>>>(A, rowptr, col, dis, nullptr, H, NN);
  gemm_f32<<<dim3(mrows, 4), gB, 0, stream>>>(H, W2, B, NN, 128, 256, b2, 0, 1);
  colmax_kernel<<<256, gB, 0, stream>>>(B, maxkey, NN);
  // stage 3: t3 = tanh(AX@W3 + b3) -> A  (t1 dead)
  gemm_f32<<<dim3(mrows, 2), gB, 0, stream>>>(AX, W3, A, NN, 64, 128, b3, 0, 1);
  // stage 4: A3 = agg(t3); i2 = tanh(A3@W4 + b4) -> B  (t2 dead)
  agg_kernel<128, false><<<aggB, gB, 0, stream>>>(A, rowptr, col, dis, nullptr, H, NN);
  gemm_f32<<<dim3(mrows, 4), gB, 0, stream>>>(H, W4, B, NN, 128, 256, b4, 0, 1);
  // stage 5: G = crow + i2@W7b + x@W7c -> H [N,128]; out = tanh(agg(G) + b7)
  crow_kernel<<<1, 128, 0, stream>>>(maxkey, W7, crow);
  gemm_f32<<<dim3(mrows, 2), gB, 0, stream>>>(B, W7 + 256 * 128, H, NN, 256, 128, crow, 0, 0);
  gemm_f32<<<dim3(mrows, 2), gB, 0, stream>>>(x, W7 + 512 * 128, H, NN, 64, 128, nullptr, 1, 0);
  agg_kernel<128, true><<<aggB, gB, 0, stream>>>(H, rowptr, col, dis, b7, out, NN);
}

// Round 8
// 519.334 us; speedup vs baseline: 1.5231x; 1.1873x over previous
//
#include <hip/hip_runtime.h>
#include <hip/hip_bf16.h>
#include <cstdint>
#include <cstddef>

#define NN 50000
#define EE 400000

typedef __attribute__((ext_vector_type(8))) __bf16 bf16x8;
typedef __attribute__((ext_vector_type(4))) float f32x4;

// ---------------- helpers ----------------
static __device__ __forceinline__ float dec_key(unsigned k) {
  return (k & 0x80000000u) ? __uint_as_float(k & 0x7fffffffu) : __uint_as_float(~k);
}
static __device__ __forceinline__ unsigned enc_key(float f) {
  unsigned b = __float_as_uint(f);
  return (f >= 0.f) ? (b | 0x80000000u) : ~b;
}

// ---------------- CSR build ----------------
__global__ void count_kernel(const int* __restrict__ dst, int* __restrict__ cnt, int e) {
  int i = blockIdx.x * blockDim.x + threadIdx.x;
  if (i < e) atomicAdd(&cnt[dst[i]], 1);
}

__global__ void dis_kernel(const int* __restrict__ cnt, float* __restrict__ dis, int n) {
  int i = blockIdx.x * blockDim.x + threadIdx.x;
  if (i < n) dis[i] = rsqrtf((float)cnt[i] + 1.0f);
}

// hierarchical scan: 1024 elems per block (4/thread), shuffle wave-scan
#define SCAN_CHUNK 1024
__global__ __launch_bounds__(256) void scan1_kernel(const int* __restrict__ cnt,
                                                    int* __restrict__ rowptr,
                                                    int* __restrict__ bsum, int n) {
  int b = blockIdx.x;
  int base = b * SCAN_CHUNK;
  int t = threadIdx.x;
  int v[4];
  int s = 0;
#pragma unroll
  for (int i = 0; i < 4; ++i) {
    int idx = base + t * 4 + i;
    v[i] = (idx < n) ? cnt[idx] : 0;
    s += v[i];
  }
  int lane = t & 63, w = t >> 6;
  int inc = s;
#pragma unroll
  for (int off = 1; off < 64; off <<= 1) {
    int o = __shfl_up(inc, off, 64);
    if (lane >= off) inc += o;
  }
  __shared__ int wsum[4];
  if (lane == 63) wsum[w] = inc;
  __syncthreads();
  int woff = 0;
  for (int i = 0; i < w; ++i) woff += wsum[i];
  int run = woff + inc - s;
#pragma unroll
  for (int i = 0; i < 4; ++i) {
    int idx = base + t * 4 + i;
    if (idx < n) rowptr[idx] = run;
    run += v[i];
  }
  if (t == 255) bsum[b] = woff + inc;
}

__global__ void scan2_kernel(int* __restrict__ bsum, int nb) {
  int t = threadIdx.x;
  int v = (t < nb) ? bsum[t] : 0;
  int s = v;
#pragma unroll
  for (int off = 1; off < 64; off <<= 1) {
    int o = __shfl_up(s, off, 64);
    if (t >= off) s += o;
  }
  if (t < nb) bsum[t] = s - v;
}

__global__ __launch_bounds__(256) void scan3_kernel(int* __restrict__ rowptr,
                                                    const int* __restrict__ bsum, int n, int total) {
  int i = blockIdx.x * blockDim.x + threadIdx.x;
  if (i < n) rowptr[i] += bsum[i >> 10];
  if (i == 0) rowptr[n] = total;
}

__global__ void fill_kernel(const int* __restrict__ src, const int* __restrict__ dst,
                            const int* __restrict__ rowptr, int* __restrict__ cursor,
                            int* __restrict__ col, int e) {
  int i = blockIdx.x * blockDim.x + threadIdx.x;
  if (i < e) {
    int d = dst[i];
    int p = atomicAdd(&cursor[d], 1);
    col[rowptr[d] + p] = src[i];
  }
}

// ---------------- f32 GEMM (small K=64 stages): C = A@W, fused epilogue ----------------
#define BM 64
#define BN 64
#define BK 16

__global__ __launch_bounds__(256) void gemm_f32(
    const float* __restrict__ A, const float* __restrict__ W, float* __restrict__ C,
    int M, int K, int Nout, const float* __restrict__ colAdd, int accumulate, int doTanh) {
  __shared__ float As[BK][BM + 4];
  __shared__ float Ws[BK][BN];
  int tid = threadIdx.x;
  int row0 = blockIdx.x * BM;
  int col0 = blockIdx.y * BN;
  int tx = tid & 15;
  int ty = tid >> 4;
  float acc[4][4] = {};
  for (int k0 = 0; k0 < K; k0 += BK) {
#pragma unroll
    for (int i = 0; i < 4; ++i) {
      int idx = tid + i * 256;
      int r = idx >> 4, c = idx & 15;
      int gr = row0 + r;
      float v = (gr < M) ? A[(size_t)gr * K + k0 + c] : 0.f;
      As[c][r] = v;
    }
#pragma unroll
    for (int i = 0; i < 4; ++i) {
      int idx = tid + i * 256;
      int r = idx >> 6, c = idx & 63;
      Ws[r][c] = W[(size_t)(k0 + r) * Nout + col0 + c];
    }
    __syncthreads();
#pragma unroll
    for (int kk = 0; kk < BK; ++kk) {
      float4 av = *(const float4*)&As[kk][ty * 4];
      float4 wv = *(const float4*)&Ws[kk][tx * 4];
      float a[4] = {av.x, av.y, av.z, av.w};
      float w[4] = {wv.x, wv.y, wv.z, wv.w};
#pragma unroll
      for (int i = 0; i < 4; ++i)
#pragma unroll
        for (int j = 0; j < 4; ++j) acc[i][j] = fmaf(a[i], w[j], acc[i][j]);
    }
    __syncthreads();
  }
#pragma unroll
  for (int i = 0; i < 4; ++i) {
    int gr = row0 + ty * 4 + i;
    if (gr >= M) continue;
#pragma unroll
    for (int j = 0; j < 4; ++j) {
      int gc = col0 + tx * 4 + j;
      size_t idx = (size_t)gr * Nout + gc;
      float v = acc[i][j];
      if (colAdd) v += colAdd[gc];
      if (accumulate) v += C[idx];
      if (doTanh) v = tanhf(v);
      C[idx] = v;
    }
  }
}

// ---------------- bf16 MFMA GEMM (big stages): C = A@W, fused epilogue ----------------
// 128x64 block tile, BK=64, 4 waves each owning 64x32.
// f32 global -> bf16 (RNE) -> XOR-swizzled LDS; B stored transposed so both
// A and B fragments are contiguous ds_read_b128. A/B slots use the SAME
// k<->slot convention -> result invariant to HW internal k-order; C/D layout
// per guide: col = lane&15, row = (lane>>4)*4 + reg.
#define TM 128
#define TN 64
#define TK 64

__global__ __launch_bounds__(256) void gemm_mfma(
    const float* __restrict__ A, const float* __restrict__ W, float* __restrict__ C,
    int M, int K, int Nout, const float* __restrict__ colAdd, int accumulate, int doTanh) {
  __shared__ char lds[(TM * TK + TN * TK) * 2];  // As bf16[128][64], Bt bf16[64][64]
  char* AsB = lds;
  char* BtB = lds + TM * TK * 2;
  int tid = threadIdx.x;
  int row0 = blockIdx.x * TM;
  int col0 = blockIdx.y * TN;
  int w = tid >> 6, l = tid & 63;
  int lr = l & 15, lh = l >> 4;
  int wmB = (w >> 1) * 64;  // wave row base within tile
  int wnB = (w & 1) * 32;   // wave col base within tile
  f32x4 acc[4][2] = {};
  for (int k0 = 0; k0 < K; k0 += TK) {
    if (k0) __syncthreads();
    // stage A: 4 octets (8 bf16) per thread; row-major, swz byte ^= (row&7)<<4
#pragma unroll
    for (int i = 0; i < 4; ++i) {
      int id = tid + i * 256;
      int r = id >> 3, oc = id & 7;
      int gr = row0 + r;
      float f[8];
      if (gr < M) {
        const float* ga = A + (size_t)gr * K + k0 + oc * 8;
        f32x4 v0 = *(const f32x4*)ga;
        f32x4 v1 = *(const f32x4*)(ga + 4);
        f[0] = v0.x; f[1] = v0.y; f[2] = v0.z; f[3] = v0.w;
        f[4] = v1.x; f[5] = v1.y; f[6] = v1.z; f[7] = v1.w;
      } else {
#pragma unroll
        for (int j = 0; j < 8; ++j) f[j] = 0.f;
      }
      bf16x8 sv;
#pragma unroll
      for (int j = 0; j < 8; ++j) sv[j] = (__bf16)f[j];
      int byte = (r * 128 + oc * 16) ^ ((r & 7) << 4);
      *(bf16x8*)(AsB + byte) = sv;
    }
    // stage Bt (transposed): 2 octets per thread; Bt[col][k]
#pragma unroll
    for (int i = 0; i < 2; ++i) {
      int id = tid + i * 256;
      int c = id & 63, ko = id >> 6;
      const float* gw = W + (size_t)(k0 + ko * 8) * Nout + col0 + c;
      bf16x8 sv;
#pragma unroll
      for (int j = 0; j < 8; ++j) sv[j] = (__bf16)gw[(size_t)j * Nout];
      int byte = (c * 128 + ko * 16) ^ ((c & 7) << 4);
      *(bf16x8*)(BtB + byte) = sv;
    }
    __syncthreads();
    // 2 MFMA k-steps of 32
#pragma unroll
    for (int s = 0; s < 2; ++s) {
      bf16x8 af[4], bfr[2];
#pragma unroll
      for (int mi = 0; mi < 4; ++mi) {
        int r = wmB + mi * 16 + lr;
        int byte = (r * 128 + (s * 32 + lh * 8) * 2) ^ ((r & 7) << 4);
        af[mi] = *(const bf16x8*)(AsB + byte);
      }
#pragma unroll
      for (int ni = 0; ni < 2; ++ni) {
        int c = wnB + ni * 16 + lr;
        int byte = (c * 128 + (s * 32 + lh * 8) * 2) ^ ((c & 7) << 4);
        bfr[ni] = *(const bf16x8*)(BtB + byte);
      }
#pragma unroll
      for (int mi = 0; mi < 4; ++mi)
#pragma unroll
        for (int ni = 0; ni < 2; ++ni)
          acc[mi][ni] =
              __builtin_amdgcn_mfma_f32_16x16x32_bf16(af[mi], bfr[ni], acc[mi][ni], 0, 0, 0);
    }
  }
  // epilogue: C/D layout col = lane&15, row = (lane>>4)*4 + reg
#pragma unroll
  for (int mi = 0; mi < 4; ++mi) {
#pragma unroll
    for (int ni = 0; ni < 2; ++ni) {
#pragma unroll
      for (int r = 0; r < 4; ++r) {
        int gr = row0 + wmB + mi * 16 + lh * 4 + r;
        if (gr >= M) continue;
        int gc = col0 + wnB + ni * 16 + lr;
        size_t idx = (size_t)gr * Nout + gc;
        float v = acc[mi][ni][r];
        if (colAdd) v += colAdd[gc];
        if (accumulate) v += C[idx];
        if (doTanh) v = tanhf(v);
        C[idx] = v;
      }
    }
  }
}

// ---------------- aggregation: out[d] = sum_{s in N(d)} H[s]*dis[s]*dis[d] + H[d]*dis[d]^2 ----------------
template <int F, bool EPI>
__global__ __launch_bounds__(256) void agg_kernel(
    const float* __restrict__ H, const int* __restrict__ rowptr, const int* __restrict__ col,
    const float* __restrict__ dis, const float* __restrict__ bias, float* __restrict__ out, int n) {
  constexpr int VEC = F / 64;
  int wid = (int)((blockIdx.x * blockDim.x + threadIdx.x) >> 6);
  int lane = threadIdx.x & 63;
  if (wid >= n) return;
  int node = __builtin_amdgcn_readfirstlane(wid);
  float dd = dis[node];
  float acc[VEC];
  {
    const float* hs = H + (size_t)node * F + lane * VEC;
    if constexpr (VEC == 4) {
      float4 h = *(const float4*)hs;
      acc[0] = h.x * dd * dd; acc[1] = h.y * dd * dd; acc[2] = h.z * dd * dd; acc[3] = h.w * dd * dd;
    } else if constexpr (VEC == 2) {
      float2 h = *(const float2*)hs;
      acc[0] = h.x * dd * dd; acc[1] = h.y * dd * dd;
    } else {
      acc[0] = hs[0] * dd * dd;
    }
  }
  int beg = rowptr[node], end = rowptr[node + 1];
  for (int e = beg; e < end; ++e) {
    int s = col[e];
    float w = dis[s] * dd;
    const float* hs = H + (size_t)s * F + lane * VEC;
    if constexpr (VEC == 4) {
      float4 h = *(const float4*)hs;
      acc[0] = fmaf(h.x, w, acc[0]); acc[1] = fmaf(h.y, w, acc[1]);
      acc[2] = fmaf(h.z, w, acc[2]); acc[3] = fmaf(h.w, w, acc[3]);
    } else if constexpr (VEC == 2) {
      float2 h = *(const float2*)hs;
      acc[0] = fmaf(h.x, w, acc[0]); acc[1] = fmaf(h.y, w, acc[1]);
    } else {
      acc[0] = fmaf(hs[0], w, acc[0]);
    }
  }
  float* o = out + (size_t)node * F + lane * VEC;
#pragma unroll
  for (int i = 0; i < VEC; ++i) {
    float v = acc[i];
    if constexpr (EPI) v = tanhf(v + bias[lane * VEC + i]);
    o[i] = v;
  }
}

// ---------------- per-feature global max ----------------
__global__ __launch_bounds__(256) void colmax_kernel(const float* __restrict__ T,
                                                     unsigned* __restrict__ maxkey, int n) {
  int f = threadIdx.x;  // F = 256
  float m = -2.0f;
  for (int r = blockIdx.x; r < n; r += gridDim.x) m = fmaxf(m, T[(size_t)r * 256 + f]);
  atomicMax(&maxkey[f], enc_key(m));
}

__global__ __launch_bounds__(128) void crow_kernel(const unsigned* __restrict__ maxkey,
                                                   const float* __restrict__ W7top,
                                                   float* __restrict__ crow) {
  int j = threadIdx.x;  // 128
  float s = 0.f;
  for (int f = 0; f < 256; ++f) s = fmaf(dec_key(maxkey[f]), W7top[f * 128 + j], s);
  crow[j] = s;
}

// ---------------- launch ----------------
extern "C" void kernel_launch(void* const* d_in, const int* in_sizes, int n_in,
                              void* d_out, int out_size, void* d_ws, size_t ws_size,
                              hipStream_t stream) {
  const float* x  = (const float*)d_in[0];
  const int* ei   = (const int*)d_in[1];
  const int* srcp = ei;
  const int* dstp = ei + EE;
  const float* W1 = (const float*)d_in[3];
  const float* b1 = (const float*)d_in[4];
  const float* W2 = (const float*)d_in[5];
  const float* b2 = (const float*)d_in[6];
  const float* W3 = (const float*)d_in[7];
  const float* b3 = (const float*)d_in[8];
  const float* W4 = (const float*)d_in[9];
  const float* b4 = (const float*)d_in[10];
  const float* W7 = (const float*)d_in[11];
  const float* b7 = (const float*)d_in[12];
  float* out = (float*)d_out;

  char* p = (char*)d_ws;
  auto alloc = [&](size_t bytes) -> void* {
    void* r = (void*)p;
    p += (bytes + 255) & ~(size_t)255;
    return r;
  };
  float* H  = (float*)alloc((size_t)NN * 256 * 4);  // aggregate / G buffer
  float* A  = (float*)alloc((size_t)NN * 128 * 4);  // t1 / t3
  float* B  = (float*)alloc((size_t)NN * 256 * 4);  // t2 / i2
  float* AX = (float*)alloc((size_t)NN * 64 * 4);   // agg(x), reused 2x
  float* dis = (float*)alloc((size_t)NN * 4);
  int* cnt = (int*)alloc((size_t)NN * 4);
  int* cursor = (int*)alloc((size_t)NN * 4);
  int* rowptr = (int*)alloc((size_t)(NN + 1) * 4);
  int* col = (int*)alloc((size_t)EE * 4);
  int* bsum = (int*)alloc(64 * 4);
  unsigned* maxkey = (unsigned*)alloc(256 * 4);
  float* crow = (float*)alloc(128 * 4);

  hipMemsetAsync(cnt, 0, (size_t)NN * 4, stream);
  hipMemsetAsync(cursor, 0, (size_t)NN * 4, stream);
  hipMemsetAsync(maxkey, 0, 256 * 4, stream);

  int eb = (EE + 255) / 256;
  int nb = (NN + 255) / 256;
  int nchunks = (NN + SCAN_CHUNK - 1) / SCAN_CHUNK;
  count_kernel<<<eb, 256, 0, stream>>>(dstp, cnt, EE);
  dis_kernel<<<nb, 256, 0, stream>>>(cnt, dis, NN);
  scan1_kernel<<<nchunks, 256, 0, stream>>>(cnt, rowptr, bsum, NN);
  scan2_kernel<<<1, 64, 0, stream>>>(bsum, nchunks);
  scan3_kernel<<<nb, 256, 0, stream>>>(rowptr, bsum, NN, EE);
  fill_kernel<<<eb, 256, 0, stream>>>(srcp, dstp, rowptr, cursor, col, EE);

  dim3 gB(256);
  int mrows = (NN + BM - 1) / BM;   // 782 (f32 gemm)
  int mrowsT = (NN + TM - 1) / TM;  // 391 (mfma gemm)
  int aggB = (NN + 3) / 4;          // 1 wave/node

  // AX = agg(x)  [N,64] — shared by stages 1, 3
  agg_kernel<64, false><<<aggB, gB, 0, stream>>>(x, rowptr, col, dis, nullptr, AX, NN);
  // stage 1: t1 = tanh(AX@W1 + b1) -> A  [N,128]  (f32, K=64)
  gemm_f32<<<dim3(mrows, 2), gB, 0, stream>>>(AX, W1, A, NN, 64, 128, b1, 0, 1);
  // stage 2: A1 = agg(t1); t2 = tanh(A1@W2 + b2) -> B  [N,256]  (MFMA, K=128)
  agg_kernel<128, false><<<aggB, gB, 0, stream>>>(A, rowptr, col, dis, nullptr, H, NN);
  gemm_mfma<<<dim3(mrowsT, 4), gB, 0, stream>>>(H, W2, B, NN, 128, 256, b2, 0, 1);
  colmax_kernel<<<256, gB, 0, stream>>>(B, maxkey, NN);
  // stage 3: t3 = tanh(AX@W3 + b3) -> A  (f32, K=64)
  gemm_f32<<<dim3(mrows, 2), gB, 0, stream>>>(AX, W3, A, NN, 64, 128, b3, 0, 1);
  // stage 4: A3 = agg(t3); i2 = tanh(A3@W4 + b4) -> B  (MFMA, K=128)
  agg_kernel<128, false><<<aggB, gB, 0, stream>>>(A, rowptr, col, dis, nullptr, H, NN);
  gemm_mfma<<<dim3(mrowsT, 4), gB, 0, stream>>>(H, W4, B, NN, 128, 256, b4, 0, 1);
  // stage 5: G = crow + i2@W7b (MFMA, K=256) + x@W7c (f32, K=64) -> H; out = tanh(agg(G)+b7)
  crow_kernel<<<1, 128, 0, stream>>>(maxkey, W7, crow);
  gemm_mfma<<<dim3(mrowsT, 2), gB, 0, stream>>>(B, W7 + 256 * 128, H, NN, 256, 128, crow, 0, 0);
  gemm_f32<<<dim3(mrows, 2), gB, 0, stream>>>(x, W7 + 512 * 128, H, NN, 64, 128, nullptr, 1, 0);
  agg_kernel<128, true><<<aggB, gB, 0, stream>>>(H, rowptr, col, dis, b7, out, NN);
}

// Round 10
// 495.859 us; speedup vs baseline: 1.5952x; 1.0473x over previous
//
#include <hip/hip_runtime.h>
#include <hip/hip_bf16.h>
#include <cstdint>
#include <cstddef>

#define NN 50000
#define EE 400000

typedef __attribute__((ext_vector_type(8))) __bf16 bf16x8;
typedef __attribute__((ext_vector_type(4))) float f32x4;

// ---------------- helpers ----------------
static __device__ __forceinline__ float dec_key(unsigned k) {
  return (k & 0x80000000u) ? __uint_as_float(k & 0x7fffffffu) : __uint_as_float(~k);
}
static __device__ __forceinline__ unsigned enc_key(float f) {
  unsigned b = __float_as_uint(f);
  return (f >= 0.f) ? (b | 0x80000000u) : ~b;
}

// ---------------- CSR build ----------------
__global__ void count_kernel(const int* __restrict__ dst, int* __restrict__ cnt, int e) {
  int i = blockIdx.x * blockDim.x + threadIdx.x;
  if (i < e) atomicAdd(&cnt[dst[i]], 1);
}

__global__ void dis_kernel(const int* __restrict__ cnt, float* __restrict__ dis, int n) {
  int i = blockIdx.x * blockDim.x + threadIdx.x;
  if (i < n) dis[i] = rsqrtf((float)cnt[i] + 1.0f);
}

// hierarchical scan: 1024 elems per block (4/thread), shuffle wave-scan
#define SCAN_CHUNK 1024
__global__ __launch_bounds__(256) void scan1_kernel(const int* __restrict__ cnt,
                                                    int* __restrict__ rowptr,
                                                    int* __restrict__ bsum, int n) {
  int b = blockIdx.x;
  int base = b * SCAN_CHUNK;
  int t = threadIdx.x;
  int v[4];
  int s = 0;
#pragma unroll
  for (int i = 0; i < 4; ++i) {
    int idx = base + t * 4 + i;
    v[i] = (idx < n) ? cnt[idx] : 0;
    s += v[i];
  }
  int lane = t & 63, w = t >> 6;
  int inc = s;
#pragma unroll
  for (int off = 1; off < 64; off <<= 1) {
    int o = __shfl_up(inc, off, 64);
    if (lane >= off) inc += o;
  }
  __shared__ int wsum[4];
  if (lane == 63) wsum[w] = inc;
  __syncthreads();
  int woff = 0;
  for (int i = 0; i < w; ++i) woff += wsum[i];
  int run = woff + inc - s;
#pragma unroll
  for (int i = 0; i < 4; ++i) {
    int idx = base + t * 4 + i;
    if (idx < n) rowptr[idx] = run;
    run += v[i];
  }
  if (t == 255) bsum[b] = woff + inc;
}

__global__ void scan2_kernel(int* __restrict__ bsum, int nb) {
  int t = threadIdx.x;
  int v = (t < nb) ? bsum[t] : 0;
  int s = v;
#pragma unroll
  for (int off = 1; off < 64; off <<= 1) {
    int o = __shfl_up(s, off, 64);
    if (t >= off) s += o;
  }
  if (t < nb) bsum[t] = s - v;
}

__global__ __launch_bounds__(256) void scan3_kernel(int* __restrict__ rowptr,
                                                    const int* __restrict__ bsum, int n, int total) {
  int i = blockIdx.x * blockDim.x + threadIdx.x;
  if (i < n) rowptr[i] += bsum[i >> 10];
  if (i == 0) rowptr[n] = total;
}

__global__ void fill_kernel(const int* __restrict__ src, const int* __restrict__ dst,
                            const int* __restrict__ rowptr, int* __restrict__ cursor,
                            int* __restrict__ col, int e) {
  int i = blockIdx.x * blockDim.x + threadIdx.x;
  if (i < e) {
    int d = dst[i];
    int p = atomicAdd(&cursor[d], 1);
    col[rowptr[d] + p] = src[i];
  }
}

// ---------------- f32 GEMM (small K=64 stages): C = A@W, fused epilogue ----------------
#define BM 64
#define BN 64
#define BK 16

__global__ __launch_bounds__(256) void gemm_f32(
    const float* __restrict__ A, const float* __restrict__ W, float* __restrict__ C,
    int M, int K, int Nout, const float* __restrict__ colAdd, int accumulate, int doTanh) {
  __shared__ float As[BK][BM + 4];
  __shared__ float Ws[BK][BN];
  int tid = threadIdx.x;
  int row0 = blockIdx.x * BM;
  int col0 = blockIdx.y * BN;
  int tx = tid & 15;
  int ty = tid >> 4;
  float acc[4][4] = {};
  for (int k0 = 0; k0 < K; k0 += BK) {
#pragma unroll
    for (int i = 0; i < 4; ++i) {
      int idx = tid + i * 256;
      int r = idx >> 4, c = idx & 15;
      int gr = row0 + r;
      float v = (gr < M) ? A[(size_t)gr * K + k0 + c] : 0.f;
      As[c][r] = v;
    }
#pragma unroll
    for (int i = 0; i < 4; ++i) {
      int idx = tid + i * 256;
      int r = idx >> 6, c = idx & 63;
      Ws[r][c] = W[(size_t)(k0 + r) * Nout + col0 + c];
    }
    __syncthreads();
#pragma unroll
    for (int kk = 0; kk < BK; ++kk) {
      float4 av = *(const float4*)&As[kk][ty * 4];
      float4 wv = *(const float4*)&Ws[kk][tx * 4];
      float a[4] = {av.x, av.y, av.z, av.w};
      float w[4] = {wv.x, wv.y, wv.z, wv.w};
#pragma unroll
      for (int i = 0; i < 4; ++i)
#pragma unroll
        for (int j = 0; j < 4; ++j) acc[i][j] = fmaf(a[i], w[j], acc[i][j]);
    }
    __syncthreads();
  }
#pragma unroll
  for (int i = 0; i < 4; ++i) {
    int gr = row0 + ty * 4 + i;
    if (gr >= M) continue;
#pragma unroll
    for (int j = 0; j < 4; ++j) {
      int gc = col0 + tx * 4 + j;
      size_t idx = (size_t)gr * Nout + gc;
      float v = acc[i][j];
      if (colAdd) v += colAdd[gc];
      if (accumulate) v += C[idx];
      if (doTanh) v = tanhf(v);
      C[idx] = v;
    }
  }
}

// ---------------- bf16 MFMA GEMM (big stages): C = A@W, fused epilogue ----------------
// 128x64 block tile, BK=64, 4 waves each owning 64x32.
// Optional fused per-column max (encoded atomicMax) of the tanh'd outputs —
// replaces a standalone 50MB re-read kernel (was 52us latency-bound).
#define TM 128
#define TN 64
#define TK 64

__global__ __launch_bounds__(256) void gemm_mfma(
    const float* __restrict__ A, const float* __restrict__ W, float* __restrict__ C,
    int M, int K, int Nout, const float* __restrict__ colAdd, int accumulate, int doTanh,
    unsigned* __restrict__ colmaxOut) {
  __shared__ char lds[(TM * TK + TN * TK) * 2];  // As bf16[128][64], Bt bf16[64][64]
  char* AsB = lds;
  char* BtB = lds + TM * TK * 2;
  int tid = threadIdx.x;
  int row0 = blockIdx.x * TM;
  int col0 = blockIdx.y * TN;
  int w = tid >> 6, l = tid & 63;
  int lr = l & 15, lh = l >> 4;
  int wmB = (w >> 1) * 64;  // wave row base within tile
  int wnB = (w & 1) * 32;   // wave col base within tile
  f32x4 acc[4][2] = {};
  for (int k0 = 0; k0 < K; k0 += TK) {
    if (k0) __syncthreads();
    // stage A: 4 octets (8 bf16) per thread; row-major, swz byte ^= (row&7)<<4
#pragma unroll
    for (int i = 0; i < 4; ++i) {
      int id = tid + i * 256;
      int r = id >> 3, oc = id & 7;
      int gr = row0 + r;
      float f[8];
      if (gr < M) {
        const float* ga = A + (size_t)gr * K + k0 + oc * 8;
        f32x4 v0 = *(const f32x4*)ga;
        f32x4 v1 = *(const f32x4*)(ga + 4);
        f[0] = v0.x; f[1] = v0.y; f[2] = v0.z; f[3] = v0.w;
        f[4] = v1.x; f[5] = v1.y; f[6] = v1.z; f[7] = v1.w;
      } else {
#pragma unroll
        for (int j = 0; j < 8; ++j) f[j] = 0.f;
      }
      bf16x8 sv;
#pragma unroll
      for (int j = 0; j < 8; ++j) sv[j] = (__bf16)f[j];
      int byte = (r * 128 + oc * 16) ^ ((r & 7) << 4);
      *(bf16x8*)(AsB + byte) = sv;
    }
    // stage Bt (transposed): 2 octets per thread; Bt[col][k]
#pragma unroll
    for (int i = 0; i < 2; ++i) {
      int id = tid + i * 256;
      int c = id & 63, ko = id >> 6;
      const float* gw = W + (size_t)(k0 + ko * 8) * Nout + col0 + c;
      bf16x8 sv;
#pragma unroll
      for (int j = 0; j < 8; ++j) sv[j] = (__bf16)gw[(size_t)j * Nout];
      int byte = (c * 128 + ko * 16) ^ ((c & 7) << 4);
      *(bf16x8*)(BtB + byte) = sv;
    }
    __syncthreads();
    // 2 MFMA k-steps of 32
#pragma unroll
    for (int s = 0; s < 2; ++s) {
      bf16x8 af[4], bfr[2];
#pragma unroll
      for (int mi = 0; mi < 4; ++mi) {
        int r = wmB + mi * 16 + lr;
        int byte = (r * 128 + (s * 32 + lh * 8) * 2) ^ ((r & 7) << 4);
        af[mi] = *(const bf16x8*)(AsB + byte);
      }
#pragma unroll
      for (int ni = 0; ni < 2; ++ni) {
        int c = wnB + ni * 16 + lr;
        int byte = (c * 128 + (s * 32 + lh * 8) * 2) ^ ((c & 7) << 4);
        bfr[ni] = *(const bf16x8*)(BtB + byte);
      }
#pragma unroll
      for (int mi = 0; mi < 4; ++mi)
#pragma unroll
        for (int ni = 0; ni < 2; ++ni)
          acc[mi][ni] =
              __builtin_amdgcn_mfma_f32_16x16x32_bf16(af[mi], bfr[ni], acc[mi][ni], 0, 0, 0);
    }
  }
  // epilogue: C/D layout col = lane&15, row = (lane>>4)*4 + reg
  float cmax[2] = {-2.0f, -2.0f};  // tanh outputs in (-1,1); enc_key monotone so -2 sentinel safe
#pragma unroll
  for (int mi = 0; mi < 4; ++mi) {
#pragma unroll
    for (int ni = 0; ni < 2; ++ni) {
#pragma unroll
      for (int r = 0; r < 4; ++r) {
        int gr = row0 + wmB + mi * 16 + lh * 4 + r;
        if (gr >= M) continue;
        int gc = col0 + wnB + ni * 16 + lr;
        size_t idx = (size_t)gr * Nout + gc;
        float v = acc[mi][ni][r];
        if (colAdd) v += colAdd[gc];
        if (accumulate) v += C[idx];
        if (doTanh) v = tanhf(v);
        if (colmaxOut) cmax[ni] = fmaxf(cmax[ni], v);
        C[idx] = v;
      }
    }
  }
  if (colmaxOut) {
    // lanes {lr, lr+16, lr+32, lr+48} share a column; combine then 1 atomic per col per wave
#pragma unroll
    for (int ni = 0; ni < 2; ++ni) {
      float m = cmax[ni];
      m = fmaxf(m, __shfl_xor(m, 16));
      m = fmaxf(m, __shfl_xor(m, 32));
      if (lh == 0) {
        int gc = col0 + wnB + ni * 16 + lr;
        atomicMax(&colmaxOut[gc], enc_key(m));
      }
    }
  }
}

// ---------------- aggregation: out[d] = sum_{s in N(d)} H[s]*dis[s]*dis[d] + H[d]*dis[d]^2 ----------------
template <int F, bool EPI>
__global__ __launch_bounds__(256) void agg_kernel(
    const float* __restrict__ H, const int* __restrict__ rowptr, const int* __restrict__ col,
    const float* __restrict__ dis, const float* __restrict__ bias, float* __restrict__ out, int n) {
  constexpr int VEC = F / 64;
  int wid = (int)((blockIdx.x * blockDim.x + threadIdx.x) >> 6);
  int lane = threadIdx.x & 63;
  if (wid >= n) return;
  int node = __builtin_amdgcn_readfirstlane(wid);
  float dd = dis[node];
  float acc[VEC];
  {
    const float* hs = H + (size_t)node * F + lane * VEC;
    if constexpr (VEC == 4) {
      float4 h = *(const float4*)hs;
      acc[0] = h.x * dd * dd; acc[1] = h.y * dd * dd; acc[2] = h.z * dd * dd; acc[3] = h.w * dd * dd;
    } else if constexpr (VEC == 2) {
      float2 h = *(const float2*)hs;
      acc[0] = h.x * dd * dd; acc[1] = h.y * dd * dd;
    } else {
      acc[0] = hs[0] * dd * dd;
    }
  }
  int beg = rowptr[node], end = rowptr[node + 1];
  for (int e = beg; e < end; ++e) {
    int s = col[e];
    float w = dis[s] * dd;
    const float* hs = H + (size_t)s * F + lane * VEC;
    if constexpr (VEC == 4) {
      float4 h = *(const float4*)hs;
      acc[0] = fmaf(h.x, w, acc[0]); acc[1] = fmaf(h.y, w, acc[1]);
      acc[2] = fmaf(h.z, w, acc[2]); acc[3] = fmaf(h.w, w, acc[3]);
    } else if constexpr (VEC == 2) {
      float2 h = *(const float2*)hs;
      acc[0] = fmaf(h.x, w, acc[0]); acc[1] = fmaf(h.y, w, acc[1]);
    } else {
      acc[0] = fmaf(hs[0], w, acc[0]);
    }
  }
  float* o = out + (size_t)node * F + lane * VEC;
#pragma unroll
  for (int i = 0; i < VEC; ++i) {
    float v = acc[i];
    if constexpr (EPI) v = tanhf(v + bias[lane * VEC + i]);
    o[i] = v;
  }
}

__global__ __launch_bounds__(128) void crow_kernel(const unsigned* __restrict__ maxkey,
                                                   const float* __restrict__ W7top,
                                                   float* __restrict__ crow) {
  int j = threadIdx.x;  // 128
  float s = 0.f;
  for (int f = 0; f < 256; ++f) s = fmaf(dec_key(maxkey[f]), W7top[f * 128 + j], s);
  crow[j] = s;
}

// ---------------- launch ----------------
extern "C" void kernel_launch(void* const* d_in, const int* in_sizes, int n_in,
                              void* d_out, int out_size, void* d_ws, size_t ws_size,
                              hipStream_t stream) {
  const float* x  = (const float*)d_in[0];
  const int* ei   = (const int*)d_in[1];
  const int* srcp = ei;
  const int* dstp = ei + EE;
  const float* W1 = (const float*)d_in[3];
  const float* b1 = (const float*)d_in[4];
  const float* W2 = (const float*)d_in[5];
  const float* b2 = (const float*)d_in[6];
  const float* W3 = (const float*)d_in[7];
  const float* b3 = (const float*)d_in[8];
  const float* W4 = (const float*)d_in[9];
  const float* b4 = (const float*)d_in[10];
  const float* W7 = (const float*)d_in[11];
  const float* b7 = (const float*)d_in[12];
  float* out = (float*)d_out;

  char* p = (char*)d_ws;
  auto alloc = [&](size_t bytes) -> void* {
    void* r = (void*)p;
    p += (bytes + 255) & ~(size_t)255;
    return r;
  };
  float* H  = (float*)alloc((size_t)NN * 256 * 4);  // aggregate / G buffer
  float* A  = (float*)alloc((size_t)NN * 128 * 4);  // t1 / t3
  float* B  = (float*)alloc((size_t)NN * 256 * 4);  // t2 / i2
  float* AX = (float*)alloc((size_t)NN * 64 * 4);   // agg(x), reused 2x
  float* dis = (float*)alloc((size_t)NN * 4);
  int* cnt = (int*)alloc((size_t)NN * 4);
  int* cursor = (int*)alloc((size_t)NN * 4);
  int* rowptr = (int*)alloc((size_t)(NN + 1) * 4);
  int* col = (int*)alloc((size_t)EE * 4);
  int* bsum = (int*)alloc(64 * 4);
  unsigned* maxkey = (unsigned*)alloc(256 * 4);
  float* crow = (float*)alloc(128 * 4);

  hipMemsetAsync(cnt, 0, (size_t)NN * 4, stream);
  hipMemsetAsync(cursor, 0, (size_t)NN * 4, stream);
  hipMemsetAsync(maxkey, 0, 256 * 4, stream);

  int eb = (EE + 255) / 256;
  int nb = (NN + 255) / 256;
  int nchunks = (NN + SCAN_CHUNK - 1) / SCAN_CHUNK;
  count_kernel<<<eb, 256, 0, stream>>>(dstp, cnt, EE);
  dis_kernel<<<nb, 256, 0, stream>>>(cnt, dis, NN);
  scan1_kernel<<<nchunks, 256, 0, stream>>>(cnt, rowptr, bsum, NN);
  scan2_kernel<<<1, 64, 0, stream>>>(bsum, nchunks);
  scan3_kernel<<<nb, 256, 0, stream>>>(rowptr, bsum, NN, EE);
  fill_kernel<<<eb, 256, 0, stream>>>(srcp, dstp, rowptr, cursor, col, EE);

  dim3 gB(256);
  int mrows = (NN + BM - 1) / BM;   // 782 (f32 gemm)
  int mrowsT = (NN + TM - 1) / TM;  // 391 (mfma gemm)
  int aggB = (NN + 3) / 4;          // 1 wave/node

  // AX = agg(x)  [N,64] — shared by stages 1, 3
  agg_kernel<64, false><<<aggB, gB, 0, stream>>>(x, rowptr, col, dis, nullptr, AX, NN);
  // stage 1: t1 = tanh(AX@W1 + b1) -> A  [N,128]  (f32, K=64)
  gemm_f32<<<dim3(mrows, 2), gB, 0, stream>>>(AX, W1, A, NN, 64, 128, b1, 0, 1);
  // stage 2: A1 = agg(t1); t2 = tanh(A1@W2 + b2) -> B  [N,256]  (MFMA, K=128, fused colmax)
  agg_kernel<128, false><<<aggB, gB, 0, stream>>>(A, rowptr, col, dis, nullptr, H, NN);
  gemm_mfma<<<dim3(mrowsT, 4), gB, 0, stream>>>(H, W2, B, NN, 128, 256, b2, 0, 1, maxkey);
  // stage 3: t3 = tanh(AX@W3 + b3) -> A  (f32, K=64)
  gemm_f32<<<dim3(mrows, 2), gB, 0, stream>>>(AX, W3, A, NN, 64, 128, b3, 0, 1);
  // stage 4: A3 = agg(t3); i2 = tanh(A3@W4 + b4) -> B  (MFMA, K=128)
  agg_kernel<128, false><<<aggB, gB, 0, stream>>>(A, rowptr, col, dis, nullptr, H, NN);
  gemm_mfma<<<dim3(mrowsT, 4), gB, 0, stream>>>(H, W4, B, NN, 128, 256, b4, 0, 1, nullptr);
  // stage 5: G = crow + i2@W7b (MFMA, K=256) + x@W7c (f32, K=64) -> H; out = tanh(agg(G)+b7)
  crow_kernel<<<1, 128, 0, stream>>>(maxkey, W7, crow);
  gemm_mfma<<<dim3(mrowsT, 2), gB, 0, stream>>>(B, W7 + 256 * 128, H, NN, 256, 128, crow, 0, 0, nullptr);
  gemm_f32<<<dim3(mrows, 2), gB, 0, stream>>>(x, W7 + 512 * 128, H, NN, 64, 128, nullptr, 1, 0);
  agg_kernel<128, true><<<aggB, gB, 0, stream>>>(H, rowptr, col, dis, b7, out, NN);
}

// Round 11
// 477.365 us; speedup vs baseline: 1.6570x; 1.0387x over previous
//
#include <hip/hip_runtime.h>
#include <hip/hip_bf16.h>
#include <cstdint>
#include <cstddef>

#define NN 50000
#define EE 400000

typedef __attribute__((ext_vector_type(8))) __bf16 bf16x8;
typedef __attribute__((ext_vector_type(4))) float f32x4;

// ---------------- helpers ----------------
static __device__ __forceinline__ float dec_key(unsigned k) {
  return (k & 0x80000000u) ? __uint_as_float(k & 0x7fffffffu) : __uint_as_float(~k);
}
static __device__ __forceinline__ unsigned enc_key(float f) {
  unsigned b = __float_as_uint(f);
  return (f >= 0.f) ? (b | 0x80000000u) : ~b;
}

// ---------------- CSR build ----------------
__global__ void count_kernel(const int* __restrict__ dst, int* __restrict__ cnt, int e) {
  int i = blockIdx.x * blockDim.x + threadIdx.x;
  if (i < e) atomicAdd(&cnt[dst[i]], 1);
}

__global__ void dis_kernel(const int* __restrict__ cnt, float* __restrict__ dis, int n) {
  int i = blockIdx.x * blockDim.x + threadIdx.x;
  if (i < n) dis[i] = rsqrtf((float)cnt[i] + 1.0f);
}

// hierarchical scan: 1024 elems per block (4/thread), shuffle wave-scan
#define SCAN_CHUNK 1024
__global__ __launch_bounds__(256) void scan1_kernel(const int* __restrict__ cnt,
                                                    int* __restrict__ rowptr,
                                                    int* __restrict__ bsum, int n) {
  int b = blockIdx.x;
  int base = b * SCAN_CHUNK;
  int t = threadIdx.x;
  int v[4];
  int s = 0;
#pragma unroll
  for (int i = 0; i < 4; ++i) {
    int idx = base + t * 4 + i;
    v[i] = (idx < n) ? cnt[idx] : 0;
    s += v[i];
  }
  int lane = t & 63, w = t >> 6;
  int inc = s;
#pragma unroll
  for (int off = 1; off < 64; off <<= 1) {
    int o = __shfl_up(inc, off, 64);
    if (lane >= off) inc += o;
  }
  __shared__ int wsum[4];
  if (lane == 63) wsum[w] = inc;
  __syncthreads();
  int woff = 0;
  for (int i = 0; i < w; ++i) woff += wsum[i];
  int run = woff + inc - s;
#pragma unroll
  for (int i = 0; i < 4; ++i) {
    int idx = base + t * 4 + i;
    if (idx < n) rowptr[idx] = run;
    run += v[i];
  }
  if (t == 255) bsum[b] = woff + inc;
}

__global__ void scan2_kernel(int* __restrict__ bsum, int nb) {
  int t = threadIdx.x;
  int v = (t < nb) ? bsum[t] : 0;
  int s = v;
#pragma unroll
  for (int off = 1; off < 64; off <<= 1) {
    int o = __shfl_up(s, off, 64);
    if (t >= off) s += o;
  }
  if (t < nb) bsum[t] = s - v;
}

__global__ __launch_bounds__(256) void scan3_kernel(int* __restrict__ rowptr,
                                                    const int* __restrict__ bsum, int n, int total) {
  int i = blockIdx.x * blockDim.x + threadIdx.x;
  if (i < n) rowptr[i] += bsum[i >> 10];
  if (i == 0) rowptr[n] = total;
}

__global__ void fill_kernel(const int* __restrict__ src, const int* __restrict__ dst,
                            const int* __restrict__ rowptr, int* __restrict__ cursor,
                            int* __restrict__ col, int e) {
  int i = blockIdx.x * blockDim.x + threadIdx.x;
  if (i < e) {
    int d = dst[i];
    int p = atomicAdd(&cursor[d], 1);
    col[rowptr[d] + p] = src[i];
  }
}

// ---------------- weight cvt+transpose: Wt[n][k] = bf16(W[k][n]) ----------------
__global__ __launch_bounds__(256) void wcvt_kernel(const float* __restrict__ W,
                                                   __bf16* __restrict__ Wt, int K, int Nout) {
  int idx = blockIdx.x * blockDim.x + threadIdx.x;
  if (idx < K * Nout) {
    int n = idx / K, k = idx - n * K;
    Wt[idx] = (__bf16)W[(size_t)k * Nout + n];
  }
}

// ---------------- f32 GEMM (small K=64 stages): C = A@W, fused epilogue ----------------
#define BM 64
#define BN 64
#define BK 16

__global__ __launch_bounds__(256) void gemm_f32(
    const float* __restrict__ A, const float* __restrict__ W, float* __restrict__ C,
    int M, int K, int Nout, const float* __restrict__ colAdd, int accumulate, int doTanh) {
  __shared__ float As[BK][BM + 4];
  __shared__ float Ws[BK][BN];
  int tid = threadIdx.x;
  int row0 = blockIdx.x * BM;
  int col0 = blockIdx.y * BN;
  int tx = tid & 15;
  int ty = tid >> 4;
  float acc[4][4] = {};
  for (int k0 = 0; k0 < K; k0 += BK) {
#pragma unroll
    for (int i = 0; i < 4; ++i) {
      int idx = tid + i * 256;
      int r = idx >> 4, c = idx & 15;
      int gr = row0 + r;
      float v = (gr < M) ? A[(size_t)gr * K + k0 + c] : 0.f;
      As[c][r] = v;
    }
#pragma unroll
    for (int i = 0; i < 4; ++i) {
      int idx = tid + i * 256;
      int r = idx >> 6, c = idx & 63;
      Ws[r][c] = W[(size_t)(k0 + r) * Nout + col0 + c];
    }
    __syncthreads();
#pragma unroll
    for (int kk = 0; kk < BK; ++kk) {
      float4 av = *(const float4*)&As[kk][ty * 4];
      float4 wv = *(const float4*)&Ws[kk][tx * 4];
      float a[4] = {av.x, av.y, av.z, av.w};
      float w[4] = {wv.x, wv.y, wv.z, wv.w};
#pragma unroll
      for (int i = 0; i < 4; ++i)
#pragma unroll
        for (int j = 0; j < 4; ++j) acc[i][j] = fmaf(a[i], w[j], acc[i][j]);
    }
    __syncthreads();
  }
#pragma unroll
  for (int i = 0; i < 4; ++i) {
    int gr = row0 + ty * 4 + i;
    if (gr >= M) continue;
#pragma unroll
    for (int j = 0; j < 4; ++j) {
      int gc = col0 + tx * 4 + j;
      size_t idx = (size_t)gr * Nout + gc;
      float v = acc[i][j];
      if (colAdd) v += colAdd[gc];
      if (accumulate) v += C[idx];
      if (doTanh) v = tanhf(v);
      C[idx] = v;
    }
  }
}

// ---------------- bf16 MFMA GEMM: A[M,K](bf16) @ Wt[Nout,K](bf16, pre-transposed) ----------------
// 128x64 tile, BK=64, 4 waves each 64x32. Staging is pure 16B copies (no cvt).
// Output: Cf (f32) and/or Ch (bf16), either may be null (stage-2 stores nothing;
// its only consumer is the fused in-register colmax).
#define TM 128
#define TN 64
#define TK 64

__global__ __launch_bounds__(256) void gemm_mfma(
    const __bf16* __restrict__ A, const __bf16* __restrict__ Wt,
    float* __restrict__ Cf, __bf16* __restrict__ Ch,
    int M, int K, int Nout, const float* __restrict__ colAdd, int doTanh,
    unsigned* __restrict__ colmaxOut) {
  __shared__ char lds[(TM * TK + TN * TK) * 2];  // As bf16[128][64], Bt bf16[64][64]
  char* AsB = lds;
  char* BtB = lds + TM * TK * 2;
  int tid = threadIdx.x;
  int row0 = blockIdx.x * TM;
  int col0 = blockIdx.y * TN;
  int w = tid >> 6, l = tid & 63;
  int lr = l & 15, lh = l >> 4;
  int wmB = (w >> 1) * 64;  // wave row base within tile
  int wnB = (w & 1) * 32;   // wave col base within tile
  f32x4 acc[4][2] = {};
  for (int k0 = 0; k0 < K; k0 += TK) {
    if (k0) __syncthreads();
    // stage A: 4 octets (16B) per thread, swz byte ^= (row&7)<<4
#pragma unroll
    for (int i = 0; i < 4; ++i) {
      int id = tid + i * 256;
      int r = id >> 3, oc = id & 7;
      int gr = row0 + r;
      bf16x8 sv;
      if (gr < M) sv = *(const bf16x8*)(A + (size_t)gr * K + k0 + oc * 8);
      else sv = bf16x8{};
      int byte = (r * 128 + oc * 16) ^ ((r & 7) << 4);
      *(bf16x8*)(AsB + byte) = sv;
    }
    // stage Bt: 2 octets per thread from pre-transposed bf16 weights
#pragma unroll
    for (int i = 0; i < 2; ++i) {
      int id = tid + i * 256;
      int c = id >> 3, oc = id & 7;
      bf16x8 sv = *(const bf16x8*)(Wt + (size_t)(col0 + c) * K + k0 + oc * 8);
      int byte = (c * 128 + oc * 16) ^ ((c & 7) << 4);
      *(bf16x8*)(BtB + byte) = sv;
    }
    __syncthreads();
    // 2 MFMA k-steps of 32
#pragma unroll
    for (int s = 0; s < 2; ++s) {
      bf16x8 af[4], bfr[2];
#pragma unroll
      for (int mi = 0; mi < 4; ++mi) {
        int r = wmB + mi * 16 + lr;
        int byte = (r * 128 + (s * 32 + lh * 8) * 2) ^ ((r & 7) << 4);
        af[mi] = *(const bf16x8*)(AsB + byte);
      }
#pragma unroll
      for (int ni = 0; ni < 2; ++ni) {
        int c = wnB + ni * 16 + lr;
        int byte = (c * 128 + (s * 32 + lh * 8) * 2) ^ ((c & 7) << 4);
        bfr[ni] = *(const bf16x8*)(BtB + byte);
      }
#pragma unroll
      for (int mi = 0; mi < 4; ++mi)
#pragma unroll
        for (int ni = 0; ni < 2; ++ni)
          acc[mi][ni] =
              __builtin_amdgcn_mfma_f32_16x16x32_bf16(af[mi], bfr[ni], acc[mi][ni], 0, 0, 0);
    }
  }
  // epilogue: C/D layout col = lane&15, row = (lane>>4)*4 + reg
  float cmax[2] = {-2.0f, -2.0f};  // tanh outputs in (-1,1); enc_key monotone so -2 sentinel safe
#pragma unroll
  for (int mi = 0; mi < 4; ++mi) {
#pragma unroll
    for (int ni = 0; ni < 2; ++ni) {
#pragma unroll
      for (int r = 0; r < 4; ++r) {
        int gr = row0 + wmB + mi * 16 + lh * 4 + r;
        if (gr >= M) continue;
        int gc = col0 + wnB + ni * 16 + lr;
        size_t idx = (size_t)gr * Nout + gc;
        float v = acc[mi][ni][r];
        if (colAdd) v += colAdd[gc];
        if (doTanh) v = tanhf(v);
        if (colmaxOut) cmax[ni] = fmaxf(cmax[ni], v);
        if (Cf) Cf[idx] = v;
        if (Ch) Ch[idx] = (__bf16)v;
      }
    }
  }
  if (colmaxOut) {
    // lanes {lr, lr+16, lr+32, lr+48} share a column; combine then 1 atomic per col per wave
#pragma unroll
    for (int ni = 0; ni < 2; ++ni) {
      float m = cmax[ni];
      m = fmaxf(m, __shfl_xor(m, 16));
      m = fmaxf(m, __shfl_xor(m, 32));
      if (lh == 0) {
        int gc = col0 + wnB + ni * 16 + lr;
        atomicMax(&colmaxOut[gc], enc_key(m));
      }
    }
  }
}

// ---------------- aggregation: out[d] = sum_{s in N(d)} H[s]*dis[s]*dis[d] + H[d]*dis[d]^2 ----------------
// OT = float or __bf16 output (bf16 out adds NO rounding vs the bf16 MFMA that consumes it)
template <int F, bool EPI, typename OT>
__global__ __launch_bounds__(256) void agg_kernel(
    const float* __restrict__ H, const int* __restrict__ rowptr, const int* __restrict__ col,
    const float* __restrict__ dis, const float* __restrict__ bias, OT* __restrict__ out, int n) {
  constexpr int VEC = F / 64;
  int wid = (int)((blockIdx.x * blockDim.x + threadIdx.x) >> 6);
  int lane = threadIdx.x & 63;
  if (wid >= n) return;
  int node = __builtin_amdgcn_readfirstlane(wid);
  float dd = dis[node];
  float acc[VEC];
  {
    const float* hs = H + (size_t)node * F + lane * VEC;
    if constexpr (VEC == 4) {
      float4 h = *(const float4*)hs;
      acc[0] = h.x * dd * dd; acc[1] = h.y * dd * dd; acc[2] = h.z * dd * dd; acc[3] = h.w * dd * dd;
    } else if constexpr (VEC == 2) {
      float2 h = *(const float2*)hs;
      acc[0] = h.x * dd * dd; acc[1] = h.y * dd * dd;
    } else {
      acc[0] = hs[0] * dd * dd;
    }
  }
  int beg = rowptr[node], end = rowptr[node + 1];
  for (int e = beg; e < end; ++e) {
    int s = col[e];
    float w = dis[s] * dd;
    const float* hs = H + (size_t)s * F + lane * VEC;
    if constexpr (VEC == 4) {
      float4 h = *(const float4*)hs;
      acc[0] = fmaf(h.x, w, acc[0]); acc[1] = fmaf(h.y, w, acc[1]);
      acc[2] = fmaf(h.z, w, acc[2]); acc[3] = fmaf(h.w, w, acc[3]);
    } else if constexpr (VEC == 2) {
      float2 h = *(const float2*)hs;
      acc[0] = fmaf(h.x, w, acc[0]); acc[1] = fmaf(h.y, w, acc[1]);
    } else {
      acc[0] = fmaf(hs[0], w, acc[0]);
    }
  }
  OT* o = out + (size_t)node * F + lane * VEC;
#pragma unroll
  for (int i = 0; i < VEC; ++i) {
    float v = acc[i];
    if constexpr (EPI) v = tanhf(v + bias[lane * VEC + i]);
    o[i] = (OT)v;
  }
}

__global__ __launch_bounds__(128) void crow_kernel(const unsigned* __restrict__ maxkey,
                                                   const float* __restrict__ W7top,
                                                   float* __restrict__ crow) {
  int j = threadIdx.x;  // 128
  float s = 0.f;
  for (int f = 0; f < 256; ++f) s = fmaf(dec_key(maxkey[f]), W7top[f * 128 + j], s);
  crow[j] = s;
}

// ---------------- launch ----------------
extern "C" void kernel_launch(void* const* d_in, const int* in_sizes, int n_in,
                              void* d_out, int out_size, void* d_ws, size_t ws_size,
                              hipStream_t stream) {
  const float* x  = (const float*)d_in[0];
  const int* ei   = (const int*)d_in[1];
  const int* srcp = ei;
  const int* dstp = ei + EE;
  const float* W1 = (const float*)d_in[3];
  const float* b1 = (const float*)d_in[4];
  const float* W2 = (const float*)d_in[5];
  const float* b2 = (const float*)d_in[6];
  const float* W3 = (const float*)d_in[7];
  const float* b3 = (const float*)d_in[8];
  const float* W4 = (const float*)d_in[9];
  const float* b4 = (const float*)d_in[10];
  const float* W7 = (const float*)d_in[11];
  const float* b7 = (const float*)d_in[12];
  float* out = (float*)d_out;

  char* p = (char*)d_ws;
  auto alloc = [&](size_t bytes) -> void* {
    void* r = (void*)p;
    p += (bytes + 255) & ~(size_t)255;
    return r;
  };
  float*  H   = (float*)alloc((size_t)NN * 128 * 4);   // stage-5 f32 buffer
  float*  A   = (float*)alloc((size_t)NN * 128 * 4);   // t1 / t3 (f32)
  __bf16* Hb  = (__bf16*)alloc((size_t)NN * 128 * 2);  // agg output for MFMA stages
  __bf16* Bb  = (__bf16*)alloc((size_t)NN * 256 * 2);  // i2 (bf16)
  float*  AX  = (float*)alloc((size_t)NN * 64 * 4);    // agg(x), reused 2x
  __bf16* W2t = (__bf16*)alloc((size_t)256 * 128 * 2);
  __bf16* W4t = (__bf16*)alloc((size_t)256 * 128 * 2);
  __bf16* W7t = (__bf16*)alloc((size_t)128 * 256 * 2);
  float* dis = (float*)alloc((size_t)NN * 4);
  int* cnt = (int*)alloc((size_t)NN * 4);
  int* cursor = (int*)alloc((size_t)NN * 4);
  int* rowptr = (int*)alloc((size_t)(NN + 1) * 4);
  int* col = (int*)alloc((size_t)EE * 4);
  int* bsum = (int*)alloc(64 * 4);
  unsigned* maxkey = (unsigned*)alloc(256 * 4);
  float* crow = (float*)alloc(128 * 4);

  hipMemsetAsync(cnt, 0, (size_t)NN * 4, stream);
  hipMemsetAsync(cursor, 0, (size_t)NN * 4, stream);
  hipMemsetAsync(maxkey, 0, 256 * 4, stream);

  int eb = (EE + 255) / 256;
  int nb = (NN + 255) / 256;
  int nchunks = (NN + SCAN_CHUNK - 1) / SCAN_CHUNK;
  count_kernel<<<eb, 256, 0, stream>>>(dstp, cnt, EE);
  dis_kernel<<<nb, 256, 0, stream>>>(cnt, dis, NN);
  scan1_kernel<<<nchunks, 256, 0, stream>>>(cnt, rowptr, bsum, NN);
  scan2_kernel<<<1, 64, 0, stream>>>(bsum, nchunks);
  scan3_kernel<<<nb, 256, 0, stream>>>(rowptr, bsum, NN, EE);
  fill_kernel<<<eb, 256, 0, stream>>>(srcp, dstp, rowptr, cursor, col, EE);

  // weight prep (bf16, transposed) — tiny one-shot work
  wcvt_kernel<<<(256 * 128 + 255) / 256, 256, 0, stream>>>(W2, W2t, 128, 256);
  wcvt_kernel<<<(256 * 128 + 255) / 256, 256, 0, stream>>>(W4, W4t, 128, 256);
  wcvt_kernel<<<(128 * 256 + 255) / 256, 256, 0, stream>>>(W7 + 256 * 128, W7t, 256, 128);

  dim3 gB(256);
  int mrows = (NN + BM - 1) / BM;   // 782 (f32 gemm)
  int mrowsT = (NN + TM - 1) / TM;  // 391 (mfma gemm)
  int aggB = (NN + 3) / 4;          // 1 wave/node

  // AX = agg(x)  [N,64] — shared by stages 1, 3
  agg_kernel<64, false, float><<<aggB, gB, 0, stream>>>(x, rowptr, col, dis, nullptr, AX, NN);
  // stage 1: t1 = tanh(AX@W1 + b1) -> A  [N,128]  (f32, K=64)
  gemm_f32<<<dim3(mrows, 2), gB, 0, stream>>>(AX, W1, A, NN, 64, 128, b1, 0, 1);
  // stage 2: Hb = agg(t1) (bf16); colmax(tanh(Hb@W2+b2)) -> maxkey. NO store (t2 dead otherwise).
  agg_kernel<128, false, __bf16><<<aggB, gB, 0, stream>>>(A, rowptr, col, dis, nullptr, Hb, NN);
  gemm_mfma<<<dim3(mrowsT, 4), gB, 0, stream>>>(Hb, W2t, nullptr, nullptr, NN, 128, 256, b2, 1, maxkey);
  // stage 3: t3 = tanh(AX@W3 + b3) -> A  (f32, K=64)
  gemm_f32<<<dim3(mrows, 2), gB, 0, stream>>>(AX, W3, A, NN, 64, 128, b3, 0, 1);
  // stage 4: Hb = agg(t3) (bf16); i2 = tanh(Hb@W4+b4) -> Bb (bf16)
  agg_kernel<128, false, __bf16><<<aggB, gB, 0, stream>>>(A, rowptr, col, dis, nullptr, Hb, NN);
  gemm_mfma<<<dim3(mrowsT, 4), gB, 0, stream>>>(Hb, W4t, nullptr, Bb, NN, 128, 256, b4, 1, nullptr);
  // stage 5: H = crow + i2@W7b (MFMA) ; H += x@W7c (f32) ; out = tanh(agg(H)+b7)
  crow_kernel<<<1, 128, 0, stream>>>(maxkey, W7, crow);
  gemm_mfma<<<dim3(mrowsT, 2), gB, 0, stream>>>(Bb, W7t, H, nullptr, NN, 256, 128, crow, 0, nullptr);
  gemm_f32<<<dim3(mrows, 2), gB, 0, stream>>>(x, W7 + 512 * 128, H, NN, 64, 128, nullptr, 1, 0);
  agg_kernel<128, true, float><<<aggB, gB, 0, stream>>>(H, rowptr, col, dis, b7, out, NN);
}